// Round 15
// baseline (351.554 us; speedup 1.0000x reference)
//
#include <hip/hip_runtime.h>
#include <math.h>

// ---------------------------------------------------------------------------
// AttentionModel on MI355X. Round 14 (base = round 8, 210us):
//  - lstm_step BK=64: two 32-k-chunks per barrier pair (16 -> 8 iters,
//    32 -> 16 barriers), same proven single-buffer reg-prefetch schedule.
//  - enhance+mask fused into one kernel (outh in LDS; mkw frags from L2):
//    one fewer dispatch + 16.8MB outh round-trip removed.
// ---------------------------------------------------------------------------

#define Bq 8
#define Tq 2048
#define Fq 257
#define Hq 256
#define TH (Tq*Hq)       // 524288
#define KW 192           // k-window rows per 64-row t-tile
#define PLD 40           // P row stride (bf16)
#define KTLD 40          // KT row stride (bf16)
#define Mq (Bq*Tq)       // 16384
#define OLD 264          // outh LDS row stride (bf16)

typedef __bf16 bf16_t;
typedef __bf16 bf16x8 __attribute__((ext_vector_type(8)));
typedef float f32x4 __attribute__((ext_vector_type(4)));

__device__ __forceinline__ float sigf(float x) { return 1.0f / (1.0f + __expf(-x)); }
__device__ __forceinline__ float tanh_f(float x) { return 1.0f - 2.0f / (__expf(2.0f * x) + 1.0f); }

// ------------------- batched fp32 -> bf16 convert + bias fold ---------------
#define CV_X   (Mq*288)            // x padded 257->288
#define CV_FW  (256*288)           // feat_w padded
#define CV_WK  (1024*512)          // [k_Wih | k_Whh]  rows g*256+j
#define CV_WQ  (1024*512)          // [q_Wih | q_Whh]
#define CV_SC  (256*256)
#define CV_EN  (256*512)
#define CV_MK  (384*256)           // mask_w padded rows 257->384
#define CV_O1  CV_X
#define CV_O2  (CV_O1+CV_FW)
#define CV_O3  (CV_O2+CV_WK)
#define CV_O4  (CV_O3+CV_WQ)
#define CV_O5  (CV_O4+CV_SC)
#define CV_O6  (CV_O5+CV_EN)
#define CV_TOT (CV_O6+CV_MK)       // 6,135,808 = 2996 * 2048
#define CVB    (CV_TOT/8/256)      // 2996 data blocks; block CVB = bias fold

__global__ __launch_bounds__(256) void cvt_all(
    const float* __restrict__ x, const float* __restrict__ feat_w,
    const float* __restrict__ kWih, const float* __restrict__ kWhh,
    const float* __restrict__ qWih, const float* __restrict__ qWhh,
    const float* __restrict__ scorew, const float* __restrict__ enhw,
    const float* __restrict__ maskw, bf16_t* __restrict__ dst,
    const float* __restrict__ kbih, const float* __restrict__ kbhh,
    const float* __restrict__ qbih, const float* __restrict__ qbhh,
    float* __restrict__ bias_all)
{
    if (blockIdx.x == CVB) {       // bias fold: 2048 f32
        const int i0 = threadIdx.x * 8;
#pragma unroll
        for (int e = 0; e < 8; ++e) {
            const int i = i0 + e;
            bias_all[i] = (i < 1024) ? kbih[i] + kbhh[i]
                                     : qbih[i - 1024] + qbhh[i - 1024];
        }
        return;
    }
    const int base = (blockIdx.x * 256 + threadIdx.x) * 8;
    bf16_t v[8];
#pragma unroll
    for (int e = 0; e < 8; ++e) {
        const int i = base + e;
        float f;
        if (i < CV_O1)      { const int r = i / 288, c = i - r * 288;
                              f = (c < Fq) ? x[(size_t)r * Fq + c] : 0.0f; }
        else if (i < CV_O2) { const int i2 = i - CV_O1, r = i2 / 288, c = i2 - r * 288;
                              f = (c < Fq) ? feat_w[r * Fq + c] : 0.0f; }
        else if (i < CV_O3) { const int i2 = i - CV_O2, r = i2 >> 9, c = i2 & 511;
                              f = (c < 256) ? kWih[r * 256 + c] : kWhh[r * 256 + c - 256]; }
        else if (i < CV_O4) { const int i2 = i - CV_O3, r = i2 >> 9, c = i2 & 511;
                              f = (c < 256) ? qWih[r * 256 + c] : qWhh[r * 256 + c - 256]; }
        else if (i < CV_O5) { f = scorew[i - CV_O4]; }
        else if (i < CV_O6) { f = enhw[i - CV_O5]; }
        else                { const int i2 = i - CV_O6, r = i2 >> 8, c = i2 & 255;
                              f = (r < Fq) ? maskw[r * 256 + c] : 0.0f; }
        v[e] = (bf16_t)f;
    }
    *(bf16x8*)(dst + base) = *(bf16x8*)v;
}

// ---------------- bf16 MFMA NT GEMM, 64x128 tile (round-8 proven) -----------
__device__ __forceinline__ const bf16_t* seg_ptr(
    const bf16_t* __restrict__ A1, int lda1, int K1,
    const bf16_t* __restrict__ A2, int lda2, int row, int k, int col8)
{
    return (k < K1) ? A1 + (size_t)row * lda1 + k + col8
                    : A2 + (size_t)row * lda2 + (k - K1) + col8;
}

template<int ACT, bool MULX, bool BF16OUT, bool F32OUT>
__global__ __launch_bounds__(256) void gemm_mfma(
    const bf16_t* __restrict__ A1, int lda1, int K1,
    const bf16_t* __restrict__ A2, int lda2, int K2,
    const bf16_t* __restrict__ W,
    const float* __restrict__ bias,
    const float* __restrict__ xm, int ldx,
    float* __restrict__ out, bf16_t* __restrict__ outbf, int ldo, int Nlog)
{
    __shared__ __align__(16) bf16_t As[64 * 32];     // 4 KB
    __shared__ __align__(16) bf16_t Ws[128 * 32];    // 8 KB
    const int tid = threadIdx.x;
    const int lane = tid & 63;
    const int wave = tid >> 6;
    const int wr = wave >> 1, wc = wave & 1;
    const int fr = lane & 15;
    const int fo = (lane >> 4) * 8;
    const int srow = tid >> 2;
    const int scol = (tid & 3) * 8;
    const int m0 = blockIdx.y * 64, n0 = blockIdx.x * 128;

    const int K = K1 + K2;
    const int ldw = K;

    uint4 ar = *(const uint4*)seg_ptr(A1, lda1, K1, A2, lda2, m0 + srow, 0, scol);
    uint4 w0 = *(const uint4*)(W + (size_t)(n0 + srow)      * ldw + scol);
    uint4 w1 = *(const uint4*)(W + (size_t)(n0 + srow + 64) * ldw + scol);

    f32x4 acc[2][4] = {};
    for (int k0 = 0; k0 < K; k0 += 32) {
        __syncthreads();                // prior LDS reads done
        *(uint4*)&As[srow * 32 + scol]        = ar;
        *(uint4*)&Ws[srow * 32 + scol]        = w0;
        *(uint4*)&Ws[(srow + 64) * 32 + scol] = w1;
        if (k0 + 32 < K) {              // prefetch k+1 (hides under MFMA below)
            ar = *(const uint4*)seg_ptr(A1, lda1, K1, A2, lda2, m0 + srow, k0 + 32, scol);
            w0 = *(const uint4*)(W + (size_t)(n0 + srow)      * ldw + k0 + 32 + scol);
            w1 = *(const uint4*)(W + (size_t)(n0 + srow + 64) * ldw + k0 + 32 + scol);
        }
        __syncthreads();
        bf16x8 af[2], bfr[4];
#pragma unroll
        for (int i = 0; i < 2; ++i) af[i]  = *(const bf16x8*)&As[(wr * 32 + i * 16 + fr) * 32 + fo];
#pragma unroll
        for (int j = 0; j < 4; ++j) bfr[j] = *(const bf16x8*)&Ws[(wc * 64 + j * 16 + fr) * 32 + fo];
#pragma unroll
        for (int i = 0; i < 2; ++i)
#pragma unroll
            for (int j = 0; j < 4; ++j)
                acc[i][j] = __builtin_amdgcn_mfma_f32_16x16x32_bf16(af[i], bfr[j], acc[i][j], 0, 0, 0);
    }

    const int rbase = (lane >> 4) * 4;
#pragma unroll
    for (int i = 0; i < 2; ++i) {
#pragma unroll
        for (int j = 0; j < 4; ++j) {
            const int n = n0 + wc * 64 + j * 16 + fr;
            if (n >= Nlog) continue;
            const float bv = bias ? bias[n] : 0.0f;
            const int m = m0 + wr * 32 + i * 16 + rbase;
#pragma unroll
            for (int r = 0; r < 4; ++r) {
                float v = acc[i][j][r] + bv;
                if (ACT == 1) v = tanh_f(v);
                else if (ACT == 2) v = sigf(v);
                if (MULX) v *= xm[(size_t)(m + r) * ldx + n];
                if (F32OUT) out[(size_t)(m + r) * ldo + n] = v;
                if (BF16OUT) outbf[(size_t)(m + r) * ldo + n] = (bf16_t)v;
            }
        }
    }
}

// -------- LSTM step: gates = hfeat@Wih^T + hprev@Whh^T + bias, cell fused ----
// 64 rows x (32 j x 4 gates) per block; grid (8, 32, 2) = 512 blocks.
// BK=64: two 32-k-chunks per barrier pair (8 iters for K=512).
// FIRST: c_prev = 0 -> no c read, K=256.
template<bool FIRST>
__global__ __launch_bounds__(256) void lstm_step(
    const bf16_t* __restrict__ hfb,                                   // hfeat + b*TH
    const bf16_t* __restrict__ hkp, const bf16_t* __restrict__ hqp,   // prev h
    const bf16_t* __restrict__ Wall, const float* __restrict__ bias_all,
    float* __restrict__ cst,
    bf16_t* __restrict__ hk, bf16_t* __restrict__ hq)
{
    __shared__ __align__(16) bf16_t As[2][64 * 32];   // 8 KB
    __shared__ __align__(16) bf16_t Ws[2][128 * 32];  // 16 KB
    const int z = blockIdx.z;
    const bf16_t* hprev = z ? hqp : hkp;
    const bf16_t* Wz = Wall + (size_t)z * (1024 * 512);
    float* c     = cst + (size_t)z * TH;
    bf16_t* hout = z ? hq : hk;

    const int tid = threadIdx.x, lane = tid & 63, wave = tid >> 6;
    const int wr = wave >> 1, wc = wave & 1;
    const int fr = lane & 15, rg = lane >> 4, fo = rg * 8;
    const int m0 = blockIdx.y * 64;
    const int jb = blockIdx.x * 32;

    const int s0 = tid >> 2, acol = (tid & 3) * 8;
    const int s1 = s0 + 64;
    const int wn0 = ((s0 >> 5) * 256) + jb + (s0 & 31);   // gate-major strips
    const int wn1 = ((s1 >> 5) * 256) + jb + (s1 & 31);

    constexpr int NIT = FIRST ? 4 : 8;   // iters of 64-K (2 chunks each)

    // A-row pointer for 32-chunk c: hfb for c<8, hprev for c>=8
    auto aptr = [&](int cc) -> const bf16_t* {
        return (FIRST || cc < 8)
            ? hfb   + (size_t)(m0 + s0) * Hq + cc * 32 + acol
            : hprev + (size_t)(m0 + s0) * Hq + (cc - 8) * 32 + acol;
    };

    uint4 arH[2], w0H[2], w1H[2];
#pragma unroll
    for (int h = 0; h < 2; ++h) {
        arH[h] = *(const uint4*)aptr(h);
        w0H[h] = *(const uint4*)(Wz + (size_t)wn0 * 512 + h * 32 + acol);
        w1H[h] = *(const uint4*)(Wz + (size_t)wn1 * 512 + h * 32 + acol);
    }

    f32x4 acc[2][4] = {};
#pragma unroll
    for (int t = 0; t < NIT; ++t) {
        if (t) __syncthreads();          // prior LDS reads done
#pragma unroll
        for (int h = 0; h < 2; ++h) {
            *(uint4*)&As[h][s0 * 32 + acol] = arH[h];
            *(uint4*)&Ws[h][s0 * 32 + acol] = w0H[h];
            *(uint4*)&Ws[h][s1 * 32 + acol] = w1H[h];
        }
        if (t + 1 < NIT) {               // prefetch next 64-K tile
#pragma unroll
            for (int h = 0; h < 2; ++h) {
                const int cc = 2 * (t + 1) + h;
                arH[h] = *(const uint4*)aptr(cc);
                w0H[h] = *(const uint4*)(Wz + (size_t)wn0 * 512 + cc * 32 + acol);
                w1H[h] = *(const uint4*)(Wz + (size_t)wn1 * 512 + cc * 32 + acol);
            }
        }
        __syncthreads();
#pragma unroll
        for (int h = 0; h < 2; ++h) {
            bf16x8 af[2], bg[4];
#pragma unroll
            for (int i = 0; i < 2; ++i) af[i] = *(const bf16x8*)&As[h][(wr * 32 + i * 16 + fr) * 32 + fo];
#pragma unroll
            for (int g = 0; g < 4; ++g) bg[g] = *(const bf16x8*)&Ws[h][(g * 32 + wc * 16 + fr) * 32 + fo];
#pragma unroll
            for (int i = 0; i < 2; ++i)
#pragma unroll
                for (int g = 0; g < 4; ++g)
                    acc[i][g] = __builtin_amdgcn_mfma_f32_16x16x32_bf16(af[i], bg[g], acc[i][g], 0, 0, 0);
        }
    }

    // cell epilogue: thread owns 4 gates of column j for 8 rows
    const int j = jb + wc * 16 + fr;
    float bs[4];
#pragma unroll
    for (int g = 0; g < 4; ++g) bs[g] = bias_all[z * 1024 + g * 256 + j];
#pragma unroll
    for (int i = 0; i < 2; ++i)
#pragma unroll
        for (int r = 0; r < 4; ++r) {
            const int t = m0 + wr * 32 + i * 16 + rg * 4 + r;
            const size_t ix = (size_t)t * Hq + j;
            const float gi = acc[i][0][r] + bs[0];
            const float gf = acc[i][1][r] + bs[1];
            const float gg = acc[i][2][r] + bs[2];
            const float go = acc[i][3][r] + bs[3];
            const float cn = FIRST ? sigf(gi) * tanh_f(gg)
                                   : sigf(gf) * c[ix] + sigf(gi) * tanh_f(gg);
            c[ix] = cn;
            hout[ix] = (bf16_t)(sigf(go) * tanh_f(cn));
        }
}

// ---------- fused enhance + mask: out0 = x * sig( tanh([c,q]@enw+b) @ mkw + mb )
// Block = 64 rows, grid 256. Phase 1: outh (64x256) -> LDS (tanh applied).
// Phase 2: mask GEMM (K=256) with mkw B-frags from L2; sigmoid * x epilogue.
__global__ __launch_bounds__(256) void enmask(
    const bf16_t* __restrict__ cattb, const bf16_t* __restrict__ hqbf,
    const bf16_t* __restrict__ enw, const float* __restrict__ enhance_b,
    const bf16_t* __restrict__ mkw, const float* __restrict__ mask_b,
    const float* __restrict__ x, float* __restrict__ out0)
{
    __shared__ __align__(16) bf16_t As[64 * 32];        // 4 KB
    __shared__ __align__(16) bf16_t Ws[256 * 32];       // 16 KB
    __shared__ __align__(16) bf16_t outhS[64 * OLD];    // 33 KB

    const int tid = threadIdx.x, lane = tid & 63, w = tid >> 6;
    const int fr = lane & 15, rg = lane >> 4, fo = rg * 8;
    const int m0 = blockIdx.x * 64;
    const int s0 = tid >> 2, acol = (tid & 3) * 8;

    // ---- phase 1: outh = tanh([cattb|hqbf] @ enw^T + enhance_b), K=512 ----
    auto aptr1 = [&](int cc) -> const bf16_t* {
        return (cc < 8) ? cattb + (size_t)(m0 + s0) * Hq + cc * 32 + acol
                        : hqbf  + (size_t)(m0 + s0) * Hq + (cc - 8) * 32 + acol;
    };
    uint4 ar, wreg[4];
    ar = *(const uint4*)aptr1(0);
#pragma unroll
    for (int p = 0; p < 4; ++p)
        wreg[p] = *(const uint4*)(enw + (size_t)(s0 + 64 * p) * 512 + acol);

    f32x4 acc1[16] = {};
    for (int t = 0; t < 16; ++t) {
        if (t) __syncthreads();
        *(uint4*)&As[s0 * 32 + acol] = ar;
#pragma unroll
        for (int p = 0; p < 4; ++p)
            *(uint4*)&Ws[(s0 + 64 * p) * 32 + acol] = wreg[p];
        if (t + 1 < 16) {
            ar = *(const uint4*)aptr1(t + 1);
#pragma unroll
            for (int p = 0; p < 4; ++p)
                wreg[p] = *(const uint4*)(enw + (size_t)(s0 + 64 * p) * 512 + (t + 1) * 32 + acol);
        }
        __syncthreads();
        const bf16x8 af = *(const bf16x8*)&As[(w * 16 + fr) * 32 + fo];
#pragma unroll
        for (int hf = 0; hf < 16; ++hf) {
            const bf16x8 bg = *(const bf16x8*)&Ws[(hf * 16 + fr) * 32 + fo];
            acc1[hf] = __builtin_amdgcn_mfma_f32_16x16x32_bf16(af, bg, acc1[hf], 0, 0, 0);
        }
    }
    __syncthreads();     // all LDS reads of phase-1 tiles done before overwrite
#pragma unroll
    for (int hf = 0; hf < 16; ++hf) {
        const int col = hf * 16 + fr;
        const float bv = enhance_b[col];
#pragma unroll
        for (int r = 0; r < 4; ++r) {
            const int row = w * 16 + rg * 4 + r;
            outhS[row * OLD + col] = (bf16_t)tanh_f(acc1[hf][r] + bv);
        }
    }
    __syncthreads();

    // ---- phase 2: out0 = x * sigmoid(outh @ mkw^T + mask_b), K=256 ----
    for (int nt = w; nt < 6; nt += 4) {          // wave-distributed 64-col tiles
        f32x4 acc2[4][4] = {};
#pragma unroll
        for (int ks = 0; ks < 8; ++ks) {
            bf16x8 af[4], bg[4];
#pragma unroll
            for (int it = 0; it < 4; ++it)
                af[it] = *(const bf16x8*)&outhS[(it * 16 + fr) * OLD + ks * 32 + fo];
#pragma unroll
            for (int jt = 0; jt < 4; ++jt)
                bg[jt] = *(const bf16x8*)(mkw + (size_t)(nt * 64 + jt * 16 + fr) * 256 + ks * 32 + fo);
#pragma unroll
            for (int it = 0; it < 4; ++it)
#pragma unroll
                for (int jt = 0; jt < 4; ++jt)
                    acc2[it][jt] = __builtin_amdgcn_mfma_f32_16x16x32_bf16(af[it], bg[jt], acc2[it][jt], 0, 0, 0);
        }
#pragma unroll
        for (int it = 0; it < 4; ++it)
#pragma unroll
            for (int jt = 0; jt < 4; ++jt) {
                const int n = nt * 64 + jt * 16 + fr;
                if (n >= Fq) continue;
                const float mb = mask_b[n];
#pragma unroll
                for (int r = 0; r < 4; ++r) {
                    const int m = m0 + it * 16 + rg * 4 + r;
                    out0[(size_t)m * Fq + n] = x[(size_t)m * Fq + n] * sigf(acc2[it][jt][r] + mb);
                }
            }
    }
}

// ----------------------- fused banded attention (unchanged) -----------------
__global__ __launch_bounds__(256) void band_fused(
    const bf16_t* __restrict__ qsbf, const bf16_t* __restrict__ kbf,
    float* __restrict__ out1, bf16_t* __restrict__ c_att)
{
    __shared__ __align__(16) bf16_t Ks[8 * KW * 32];     // 98304 B, [h/32][j][32]
    __shared__ __align__(16) bf16_t P[6 * 64 * PLD];     // 30720 B
    __shared__ __align__(16) bf16_t KT[256 * KTLD];      // 20480 B

    const int b = blockIdx.y;
    const int t0 = blockIdx.x * 64;
    const int u0 = t0 - 128;
    const int tid = threadIdx.x, lane = tid & 63, w = tid >> 6;
    const int fr = lane & 15, rg = lane >> 4, fo = rg * 8;
    const size_t kbase = (size_t)b * Tq;

#pragma unroll
    for (int it = 0; it < 24; ++it) {
        const int idx = it * 256 + tid;
        const int n  = idx >> 5;
        const int c8 = (idx & 31) * 8;
        uint4 v = {0, 0, 0, 0};
        const int u = u0 + n;
        if (u >= 0) v = *(const uint4*)(kbf + (kbase + u) * (size_t)Hq + c8);
        *(uint4*)&Ks[((c8 >> 5) * KW + n) * 32 + (c8 & 31)] = v;
    }
    __syncthreads();

    f32x4 acc[12] = {};
    const bf16_t* qrow = qsbf + (kbase + t0 + 16 * w + fr) * (size_t)Hq;
#pragma unroll
    for (int ks = 0; ks < 8; ++ks) {
        const bf16x8 aq = *(const bf16x8*)(qrow + ks * 32 + fo);
#pragma unroll
        for (int jf = 0; jf < 12; ++jf) {
            const bf16x8 bk = *(const bf16x8*)&Ks[(ks * KW + jf * 16 + fr) * 32 + fo];
            acc[jf] = __builtin_amdgcn_mfma_f32_16x16x32_bf16(aq, bk, acc[jf], 0, 0, 0);
        }
    }

    const int jmin = (128 - t0) > 0 ? (128 - t0) : 0;
    float mx[4] = {-3e38f, -3e38f, -3e38f, -3e38f};
#pragma unroll
    for (int jf = 0; jf < 12; ++jf)
#pragma unroll
        for (int r = 0; r < 4; ++r) {
            const int i = 16 * w + rg * 4 + r;
            const int j = jf * 16 + fr;
            if (j >= i && j <= i + 128 && j >= jmin)
                mx[r] = fmaxf(mx[r], acc[jf][r]);
        }
#pragma unroll
    for (int d = 1; d < 16; d <<= 1)
#pragma unroll
        for (int r = 0; r < 4; ++r) mx[r] = fmaxf(mx[r], __shfl_xor(mx[r], d));

    float ex[12][4];
    float sm[4] = {0.0f, 0.0f, 0.0f, 0.0f};
#pragma unroll
    for (int jf = 0; jf < 12; ++jf)
#pragma unroll
        for (int r = 0; r < 4; ++r) {
            const int i = 16 * w + rg * 4 + r;
            const int j = jf * 16 + fr;
            const bool v = (j >= i && j <= i + 128 && j >= jmin);
            const float e = v ? __expf(acc[jf][r] - mx[r]) : 0.0f;
            ex[jf][r] = e;
            sm[r] += e;
        }
#pragma unroll
    for (int d = 1; d < 16; d <<= 1)
#pragma unroll
        for (int r = 0; r < 4; ++r) sm[r] += __shfl_xor(sm[r], d);
    float inv[4];
#pragma unroll
    for (int r = 0; r < 4; ++r) inv[r] = 1.0f / (sm[r] + 1e-10f);

#pragma unroll
    for (int jf = 0; jf < 12; ++jf)
#pragma unroll
        for (int r = 0; r < 4; ++r) {
            const int i = 16 * w + rg * 4 + r;
            const int j = jf * 16 + fr;
            const float wv = ex[jf][r] * inv[r];
            if (u0 + j >= 0)
                out1[(kbase + t0 + i) * (size_t)Tq + (u0 + j)] = wv;
            P[((j >> 5) * 64 + i) * PLD + (j & 31)] = (bf16_t)wv;
        }

    {
        const int c4l = (u0 > 0 ? u0 : 0) >> 2;
        const int c4r = (u0 + KW) >> 2;
        const float4 z4 = {0.0f, 0.0f, 0.0f, 0.0f};
        for (int rr = 0; rr < 16; ++rr) {
            float* rowp = out1 + (kbase + t0 + 16 * w + rr) * (size_t)Tq;
            for (int c4 = lane; c4 < c4l; c4 += 64)
                *(float4*)(rowp + 4 * c4) = z4;
            for (int c4 = c4r + lane; c4 < Tq / 4; c4 += 64)
                *(float4*)(rowp + 4 * c4) = z4;
        }
    }

    f32x4 cacc[16] = {};
    for (int jc = 0; jc < 6; ++jc) {
        __syncthreads();
#pragma unroll
        for (int it = 0; it < 4; ++it) {
            const int idx = it * 256 + tid;
            const int jl = idx >> 5;
            const int hc = (idx & 31) * 8;
            const bf16x8 kv = *(const bf16x8*)&Ks[((hc >> 5) * KW + jc * 32 + jl) * 32 + (hc & 31)];
#pragma unroll
            for (int e = 0; e < 8; ++e) KT[(hc + e) * KTLD + jl] = kv[e];
        }
        __syncthreads();
        const bf16x8 pa = *(const bf16x8*)&P[(jc * 64 + 16 * w + fr) * PLD + fo];
#pragma unroll
        for (int hf = 0; hf < 16; ++hf) {
            const bf16x8 bk = *(const bf16x8*)&KT[(hf * 16 + fr) * KTLD + fo];
            cacc[hf] = __builtin_amdgcn_mfma_f32_16x16x32_bf16(pa, bk, cacc[hf], 0, 0, 0);
        }
    }

#pragma unroll
    for (int hf = 0; hf < 16; ++hf)
#pragma unroll
        for (int r = 0; r < 4; ++r) {
            const int i = 16 * w + rg * 4 + r;
            c_att[(kbase + t0 + i) * (size_t)Hq + hf * 16 + fr] = (bf16_t)cacc[hf][r];
        }
}

// ---------------------------------------------------------------------------
extern "C" void kernel_launch(void* const* d_in, const int* in_sizes, int n_in,
                              void* d_out, int out_size, void* d_ws, size_t ws_size,
                              hipStream_t stream)
{
    (void)in_sizes; (void)n_in; (void)out_size; (void)ws_size;
    const float* x        = (const float*)d_in[0];
    const float* feat_w   = (const float*)d_in[1];
    const float* feat_b   = (const float*)d_in[2];
    const float* k_Wih    = (const float*)d_in[3];
    const float* k_Whh    = (const float*)d_in[4];
    const float* k_bih    = (const float*)d_in[5];
    const float* k_bhh    = (const float*)d_in[6];
    const float* q_Wih    = (const float*)d_in[7];
    const float* q_Whh    = (const float*)d_in[8];
    const float* q_bih    = (const float*)d_in[9];
    const float* q_bhh    = (const float*)d_in[10];
    const float* score_w  = (const float*)d_in[11];
    const float* enhance_w= (const float*)d_in[12];
    const float* enhance_b= (const float*)d_in[13];
    const float* mask_w   = (const float*)d_in[14];
    const float* mask_b   = (const float*)d_in[15];

    float* out0 = (float*)d_out;                         // (8,2048,257)
    float* out1 = out0 + (size_t)Bq * Tq * Fq;           // (8,2048,2048)

    // ---- workspace (no fills needed; every word written before read) ----
    float* cst      = (float*)d_ws;                      // 2*TH f32 (c states)
    float* bias_all = cst + (size_t)2 * TH;              // 2048 f32
    bf16_t* cvd = (bf16_t*)(bias_all + 2048);
    bf16_t* xbf     = cvd;                               // reused as qsbf later
    bf16_t* featw   = cvd + CV_O1;
    bf16_t* Wall    = cvd + CV_O2;                       // 2048 rows x 512 [k;q]
    bf16_t* scw     = cvd + CV_O4;
    bf16_t* enw     = cvd + CV_O5;
    bf16_t* mkw     = cvd + CV_O6;
    bf16_t* hfeatbf = cvd + CV_TOT;                      // Mq*256
    bf16_t* hkbf    = hfeatbf + (size_t)Mq * Hq;         // 8*TH
    bf16_t* hqbf    = hkbf + (size_t)Bq * TH;            // 8*TH
    bf16_t* cattb   = hqbf + (size_t)Bq * TH;            // Mq*256

    // 0) conversions + bias fold (one dispatch)
    cvt_all<<<CVB + 1, 256, 0, stream>>>(
        x, feat_w, k_Wih, k_Whh, q_Wih, q_Whh, score_w, enhance_w, mask_w, cvd,
        k_bih, k_bhh, q_bih, q_bhh, bias_all);

    // 1) feat: hfeatbf = tanh(x @ feat_w^T + feat_b)   grid (2, 256)
    gemm_mfma<1, false, true, false><<<dim3(2, Mq / 64), 256, 0, stream>>>(
        xbf, 288, 288, nullptr, 0, 0, featw, feat_b, nullptr, 0,
        nullptr, hfeatbf, Hq, 1 << 30);

    // 2) LSTM k & q: 8 fused steps (K=512, BK=64; b=0 writes c without reading)
    lstm_step<true><<<dim3(8, Tq / 64, 2), 256, 0, stream>>>(
        hfeatbf, nullptr, nullptr, Wall, bias_all, cst, hkbf, hqbf);
    for (int b = 1; b < Bq; ++b)
        lstm_step<false><<<dim3(8, Tq / 64, 2), 256, 0, stream>>>(
            hfeatbf + (size_t)b * TH,
            hkbf + (size_t)(b - 1) * TH, hqbf + (size_t)(b - 1) * TH,
            Wall, bias_all, cst,
            hkbf + (size_t)b * TH, hqbf + (size_t)b * TH);

    // 3) score: qsbf = q @ score_w^T  (bf16, reuses xbf)  grid (2, 256)
    bf16_t* qsbf = xbf;
    gemm_mfma<0, false, true, false><<<dim3(2, Mq / 64), 256, 0, stream>>>(
        hqbf, Hq, Hq, nullptr, 0, 0, scw, nullptr, nullptr, 0,
        nullptr, qsbf, Hq, 1 << 30);

    // 4+5) fused banded softmax + PV; writes full out1 rows
    band_fused<<<dim3(Tq / 64, Bq), 256, 0, stream>>>(qsbf, hkbf, out1, cattb);

    // 6+7) fused enhance + mask: out0 = x * sig(tanh([c,q]@enw+b) @ mkw + mb)
    enmask<<<Mq / 64, 256, 0, stream>>>(
        cattb, hqbf, enw, enhance_b, mkw, mask_b, x, out0);
}

// Round 16
// 350.730 us; speedup vs baseline: 1.0024x; 1.0024x over previous
//
#include <hip/hip_runtime.h>
#include <math.h>

// ---------------------------------------------------------------------------
// AttentionModel on MI355X. Round 14 (base = round 8, 210us):
//  - lstm_step BK=64: two 32-k-chunks per barrier pair (16 -> 8 iters,
//    32 -> 16 barriers), same proven single-buffer reg-prefetch schedule.
//  - enhance+mask fused into one kernel (outh in LDS; mkw frags from L2):
//    one fewer dispatch + 16.8MB outh round-trip removed.
// ---------------------------------------------------------------------------

#define Bq 8
#define Tq 2048
#define Fq 257
#define Hq 256
#define TH (Tq*Hq)       // 524288
#define KW 192           // k-window rows per 64-row t-tile
#define PLD 40           // P row stride (bf16)
#define KTLD 40          // KT row stride (bf16)
#define Mq (Bq*Tq)       // 16384
#define OLD 264          // outh LDS row stride (bf16)

typedef __bf16 bf16_t;
typedef __bf16 bf16x8 __attribute__((ext_vector_type(8)));
typedef float f32x4 __attribute__((ext_vector_type(4)));

__device__ __forceinline__ float sigf(float x) { return 1.0f / (1.0f + __expf(-x)); }
__device__ __forceinline__ float tanh_f(float x) { return 1.0f - 2.0f / (__expf(2.0f * x) + 1.0f); }

// ------------------- batched fp32 -> bf16 convert + bias fold ---------------
#define CV_X   (Mq*288)            // x padded 257->288
#define CV_FW  (256*288)           // feat_w padded
#define CV_WK  (1024*512)          // [k_Wih | k_Whh]  rows g*256+j
#define CV_WQ  (1024*512)          // [q_Wih | q_Whh]
#define CV_SC  (256*256)
#define CV_EN  (256*512)
#define CV_MK  (384*256)           // mask_w padded rows 257->384
#define CV_O1  CV_X
#define CV_O2  (CV_O1+CV_FW)
#define CV_O3  (CV_O2+CV_WK)
#define CV_O4  (CV_O3+CV_WQ)
#define CV_O5  (CV_O4+CV_SC)
#define CV_O6  (CV_O5+CV_EN)
#define CV_TOT (CV_O6+CV_MK)       // 6,135,808 = 2996 * 2048
#define CVB    (CV_TOT/8/256)      // 2996 data blocks; block CVB = bias fold

__global__ __launch_bounds__(256) void cvt_all(
    const float* __restrict__ x, const float* __restrict__ feat_w,
    const float* __restrict__ kWih, const float* __restrict__ kWhh,
    const float* __restrict__ qWih, const float* __restrict__ qWhh,
    const float* __restrict__ scorew, const float* __restrict__ enhw,
    const float* __restrict__ maskw, bf16_t* __restrict__ dst,
    const float* __restrict__ kbih, const float* __restrict__ kbhh,
    const float* __restrict__ qbih, const float* __restrict__ qbhh,
    float* __restrict__ bias_all)
{
    if (blockIdx.x == CVB) {       // bias fold: 2048 f32
        const int i0 = threadIdx.x * 8;
#pragma unroll
        for (int e = 0; e < 8; ++e) {
            const int i = i0 + e;
            bias_all[i] = (i < 1024) ? kbih[i] + kbhh[i]
                                     : qbih[i - 1024] + qbhh[i - 1024];
        }
        return;
    }
    const int base = (blockIdx.x * 256 + threadIdx.x) * 8;
    bf16_t v[8];
#pragma unroll
    for (int e = 0; e < 8; ++e) {
        const int i = base + e;
        float f;
        if (i < CV_O1)      { const int r = i / 288, c = i - r * 288;
                              f = (c < Fq) ? x[(size_t)r * Fq + c] : 0.0f; }
        else if (i < CV_O2) { const int i2 = i - CV_O1, r = i2 / 288, c = i2 - r * 288;
                              f = (c < Fq) ? feat_w[r * Fq + c] : 0.0f; }
        else if (i < CV_O3) { const int i2 = i - CV_O2, r = i2 >> 9, c = i2 & 511;
                              f = (c < 256) ? kWih[r * 256 + c] : kWhh[r * 256 + c - 256]; }
        else if (i < CV_O4) { const int i2 = i - CV_O3, r = i2 >> 9, c = i2 & 511;
                              f = (c < 256) ? qWih[r * 256 + c] : qWhh[r * 256 + c - 256]; }
        else if (i < CV_O5) { f = scorew[i - CV_O4]; }
        else if (i < CV_O6) { f = enhw[i - CV_O5]; }
        else                { const int i2 = i - CV_O6, r = i2 >> 8, c = i2 & 255;
                              f = (r < Fq) ? maskw[r * 256 + c] : 0.0f; }
        v[e] = (bf16_t)f;
    }
    *(bf16x8*)(dst + base) = *(bf16x8*)v;
}

// ---------------- bf16 MFMA NT GEMM, 64x128 tile (round-8 proven) -----------
__device__ __forceinline__ const bf16_t* seg_ptr(
    const bf16_t* __restrict__ A1, int lda1, int K1,
    const bf16_t* __restrict__ A2, int lda2, int row, int k, int col8)
{
    return (k < K1) ? A1 + (size_t)row * lda1 + k + col8
                    : A2 + (size_t)row * lda2 + (k - K1) + col8;
}

template<int ACT, bool MULX, bool BF16OUT, bool F32OUT>
__global__ __launch_bounds__(256) void gemm_mfma(
    const bf16_t* __restrict__ A1, int lda1, int K1,
    const bf16_t* __restrict__ A2, int lda2, int K2,
    const bf16_t* __restrict__ W,
    const float* __restrict__ bias,
    const float* __restrict__ xm, int ldx,
    float* __restrict__ out, bf16_t* __restrict__ outbf, int ldo, int Nlog)
{
    __shared__ __align__(16) bf16_t As[64 * 32];     // 4 KB
    __shared__ __align__(16) bf16_t Ws[128 * 32];    // 8 KB
    const int tid = threadIdx.x;
    const int lane = tid & 63;
    const int wave = tid >> 6;
    const int wr = wave >> 1, wc = wave & 1;
    const int fr = lane & 15;
    const int fo = (lane >> 4) * 8;
    const int srow = tid >> 2;
    const int scol = (tid & 3) * 8;
    const int m0 = blockIdx.y * 64, n0 = blockIdx.x * 128;

    const int K = K1 + K2;
    const int ldw = K;

    uint4 ar = *(const uint4*)seg_ptr(A1, lda1, K1, A2, lda2, m0 + srow, 0, scol);
    uint4 w0 = *(const uint4*)(W + (size_t)(n0 + srow)      * ldw + scol);
    uint4 w1 = *(const uint4*)(W + (size_t)(n0 + srow + 64) * ldw + scol);

    f32x4 acc[2][4] = {};
    for (int k0 = 0; k0 < K; k0 += 32) {
        __syncthreads();                // prior LDS reads done
        *(uint4*)&As[srow * 32 + scol]        = ar;
        *(uint4*)&Ws[srow * 32 + scol]        = w0;
        *(uint4*)&Ws[(srow + 64) * 32 + scol] = w1;
        if (k0 + 32 < K) {              // prefetch k+1 (hides under MFMA below)
            ar = *(const uint4*)seg_ptr(A1, lda1, K1, A2, lda2, m0 + srow, k0 + 32, scol);
            w0 = *(const uint4*)(W + (size_t)(n0 + srow)      * ldw + k0 + 32 + scol);
            w1 = *(const uint4*)(W + (size_t)(n0 + srow + 64) * ldw + k0 + 32 + scol);
        }
        __syncthreads();
        bf16x8 af[2], bfr[4];
#pragma unroll
        for (int i = 0; i < 2; ++i) af[i]  = *(const bf16x8*)&As[(wr * 32 + i * 16 + fr) * 32 + fo];
#pragma unroll
        for (int j = 0; j < 4; ++j) bfr[j] = *(const bf16x8*)&Ws[(wc * 64 + j * 16 + fr) * 32 + fo];
#pragma unroll
        for (int i = 0; i < 2; ++i)
#pragma unroll
            for (int j = 0; j < 4; ++j)
                acc[i][j] = __builtin_amdgcn_mfma_f32_16x16x32_bf16(af[i], bfr[j], acc[i][j], 0, 0, 0);
    }

    const int rbase = (lane >> 4) * 4;
#pragma unroll
    for (int i = 0; i < 2; ++i) {
#pragma unroll
        for (int j = 0; j < 4; ++j) {
            const int n = n0 + wc * 64 + j * 16 + fr;
            if (n >= Nlog) continue;
            const float bv = bias ? bias[n] : 0.0f;
            const int m = m0 + wr * 32 + i * 16 + rbase;
#pragma unroll
            for (int r = 0; r < 4; ++r) {
                float v = acc[i][j][r] + bv;
                if (ACT == 1) v = tanh_f(v);
                else if (ACT == 2) v = sigf(v);
                if (MULX) v *= xm[(size_t)(m + r) * ldx + n];
                if (F32OUT) out[(size_t)(m + r) * ldo + n] = v;
                if (BF16OUT) outbf[(size_t)(m + r) * ldo + n] = (bf16_t)v;
            }
        }
    }
}

// -------- LSTM step: gates = hfeat@Wih^T + hprev@Whh^T + bias, cell fused ----
// 64 rows x (32 j x 4 gates) per block; grid (8, 32, 2) = 512 blocks.
// BK=64: two 32-k-chunks per barrier pair (8 iters for K=512).
// FIRST: c_prev = 0 -> no c read, K=256.
template<bool FIRST>
__global__ __launch_bounds__(256) void lstm_step(
    const bf16_t* __restrict__ hfb,                                   // hfeat + b*TH
    const bf16_t* __restrict__ hkp, const bf16_t* __restrict__ hqp,   // prev h
    const bf16_t* __restrict__ Wall, const float* __restrict__ bias_all,
    float* __restrict__ cst,
    bf16_t* __restrict__ hk, bf16_t* __restrict__ hq)
{
    __shared__ __align__(16) bf16_t As[2][64 * 32];   // 8 KB
    __shared__ __align__(16) bf16_t Ws[2][128 * 32];  // 16 KB
    const int z = blockIdx.z;
    const bf16_t* hprev = z ? hqp : hkp;
    const bf16_t* Wz = Wall + (size_t)z * (1024 * 512);
    float* c     = cst + (size_t)z * TH;
    bf16_t* hout = z ? hq : hk;

    const int tid = threadIdx.x, lane = tid & 63, wave = tid >> 6;
    const int wr = wave >> 1, wc = wave & 1;
    const int fr = lane & 15, rg = lane >> 4, fo = rg * 8;
    const int m0 = blockIdx.y * 64;
    const int jb = blockIdx.x * 32;

    const int s0 = tid >> 2, acol = (tid & 3) * 8;
    const int s1 = s0 + 64;
    const int wn0 = ((s0 >> 5) * 256) + jb + (s0 & 31);   // gate-major strips
    const int wn1 = ((s1 >> 5) * 256) + jb + (s1 & 31);

    constexpr int NIT = FIRST ? 4 : 8;   // iters of 64-K (2 chunks each)

    // A-row pointer for 32-chunk c: hfb for c<8, hprev for c>=8
    auto aptr = [&](int cc) -> const bf16_t* {
        return (FIRST || cc < 8)
            ? hfb   + (size_t)(m0 + s0) * Hq + cc * 32 + acol
            : hprev + (size_t)(m0 + s0) * Hq + (cc - 8) * 32 + acol;
    };

    uint4 arH[2], w0H[2], w1H[2];
#pragma unroll
    for (int h = 0; h < 2; ++h) {
        arH[h] = *(const uint4*)aptr(h);
        w0H[h] = *(const uint4*)(Wz + (size_t)wn0 * 512 + h * 32 + acol);
        w1H[h] = *(const uint4*)(Wz + (size_t)wn1 * 512 + h * 32 + acol);
    }

    f32x4 acc[2][4] = {};
#pragma unroll
    for (int t = 0; t < NIT; ++t) {
        if (t) __syncthreads();          // prior LDS reads done
#pragma unroll
        for (int h = 0; h < 2; ++h) {
            *(uint4*)&As[h][s0 * 32 + acol] = arH[h];
            *(uint4*)&Ws[h][s0 * 32 + acol] = w0H[h];
            *(uint4*)&Ws[h][s1 * 32 + acol] = w1H[h];
        }
        if (t + 1 < NIT) {               // prefetch next 64-K tile
#pragma unroll
            for (int h = 0; h < 2; ++h) {
                const int cc = 2 * (t + 1) + h;
                arH[h] = *(const uint4*)aptr(cc);
                w0H[h] = *(const uint4*)(Wz + (size_t)wn0 * 512 + cc * 32 + acol);
                w1H[h] = *(const uint4*)(Wz + (size_t)wn1 * 512 + cc * 32 + acol);
            }
        }
        __syncthreads();
#pragma unroll
        for (int h = 0; h < 2; ++h) {
            bf16x8 af[2], bg[4];
#pragma unroll
            for (int i = 0; i < 2; ++i) af[i] = *(const bf16x8*)&As[h][(wr * 32 + i * 16 + fr) * 32 + fo];
#pragma unroll
            for (int g = 0; g < 4; ++g) bg[g] = *(const bf16x8*)&Ws[h][(g * 32 + wc * 16 + fr) * 32 + fo];
#pragma unroll
            for (int i = 0; i < 2; ++i)
#pragma unroll
                for (int g = 0; g < 4; ++g)
                    acc[i][g] = __builtin_amdgcn_mfma_f32_16x16x32_bf16(af[i], bg[g], acc[i][g], 0, 0, 0);
        }
    }

    // cell epilogue: thread owns 4 gates of column j for 8 rows
    const int j = jb + wc * 16 + fr;
    float bs[4];
#pragma unroll
    for (int g = 0; g < 4; ++g) bs[g] = bias_all[z * 1024 + g * 256 + j];
#pragma unroll
    for (int i = 0; i < 2; ++i)
#pragma unroll
        for (int r = 0; r < 4; ++r) {
            const int t = m0 + wr * 32 + i * 16 + rg * 4 + r;
            const size_t ix = (size_t)t * Hq + j;
            const float gi = acc[i][0][r] + bs[0];
            const float gf = acc[i][1][r] + bs[1];
            const float gg = acc[i][2][r] + bs[2];
            const float go = acc[i][3][r] + bs[3];
            const float cn = FIRST ? sigf(gi) * tanh_f(gg)
                                   : sigf(gf) * c[ix] + sigf(gi) * tanh_f(gg);
            c[ix] = cn;
            hout[ix] = (bf16_t)(sigf(go) * tanh_f(cn));
        }
}

// ---------- fused enhance + mask: out0 = x * sig( tanh([c,q]@enw+b) @ mkw + mb )
// Block = 64 rows, grid 256. Phase 1: outh (64x256) -> LDS (tanh applied).
// Phase 2: mask GEMM (K=256) with mkw B-frags from L2; sigmoid * x epilogue.
__global__ __launch_bounds__(256) void enmask(
    const bf16_t* __restrict__ cattb, const bf16_t* __restrict__ hqbf,
    const bf16_t* __restrict__ enw, const float* __restrict__ enhance_b,
    const bf16_t* __restrict__ mkw, const float* __restrict__ mask_b,
    const float* __restrict__ x, float* __restrict__ out0)
{
    __shared__ __align__(16) bf16_t As[64 * 32];        // 4 KB
    __shared__ __align__(16) bf16_t Ws[256 * 32];       // 16 KB
    __shared__ __align__(16) bf16_t outhS[64 * OLD];    // 33 KB

    const int tid = threadIdx.x, lane = tid & 63, w = tid >> 6;
    const int fr = lane & 15, rg = lane >> 4, fo = rg * 8;
    const int m0 = blockIdx.x * 64;
    const int s0 = tid >> 2, acol = (tid & 3) * 8;

    // ---- phase 1: outh = tanh([cattb|hqbf] @ enw^T + enhance_b), K=512 ----
    auto aptr1 = [&](int cc) -> const bf16_t* {
        return (cc < 8) ? cattb + (size_t)(m0 + s0) * Hq + cc * 32 + acol
                        : hqbf  + (size_t)(m0 + s0) * Hq + (cc - 8) * 32 + acol;
    };
    uint4 ar, wreg[4];
    ar = *(const uint4*)aptr1(0);
#pragma unroll
    for (int p = 0; p < 4; ++p)
        wreg[p] = *(const uint4*)(enw + (size_t)(s0 + 64 * p) * 512 + acol);

    f32x4 acc1[16] = {};
    for (int t = 0; t < 16; ++t) {
        if (t) __syncthreads();
        *(uint4*)&As[s0 * 32 + acol] = ar;
#pragma unroll
        for (int p = 0; p < 4; ++p)
            *(uint4*)&Ws[(s0 + 64 * p) * 32 + acol] = wreg[p];
        if (t + 1 < 16) {
            ar = *(const uint4*)aptr1(t + 1);
#pragma unroll
            for (int p = 0; p < 4; ++p)
                wreg[p] = *(const uint4*)(enw + (size_t)(s0 + 64 * p) * 512 + (t + 1) * 32 + acol);
        }
        __syncthreads();
        const bf16x8 af = *(const bf16x8*)&As[(w * 16 + fr) * 32 + fo];
#pragma unroll
        for (int hf = 0; hf < 16; ++hf) {
            const bf16x8 bg = *(const bf16x8*)&Ws[(hf * 16 + fr) * 32 + fo];
            acc1[hf] = __builtin_amdgcn_mfma_f32_16x16x32_bf16(af, bg, acc1[hf], 0, 0, 0);
        }
    }
    __syncthreads();     // all LDS reads of phase-1 tiles done before overwrite
#pragma unroll
    for (int hf = 0; hf < 16; ++hf) {
        const int col = hf * 16 + fr;
        const float bv = enhance_b[col];
#pragma unroll
        for (int r = 0; r < 4; ++r) {
            const int row = w * 16 + rg * 4 + r;
            outhS[row * OLD + col] = (bf16_t)tanh_f(acc1[hf][r] + bv);
        }
    }
    __syncthreads();

    // ---- phase 2: out0 = x * sigmoid(outh @ mkw^T + mask_b), K=256 ----
    for (int nt = w; nt < 6; nt += 4) {          // wave-distributed 64-col tiles
        f32x4 acc2[4][4] = {};
#pragma unroll
        for (int ks = 0; ks < 8; ++ks) {
            bf16x8 af[4], bg[4];
#pragma unroll
            for (int it = 0; it < 4; ++it)
                af[it] = *(const bf16x8*)&outhS[(it * 16 + fr) * OLD + ks * 32 + fo];
#pragma unroll
            for (int jt = 0; jt < 4; ++jt)
                bg[jt] = *(const bf16x8*)(mkw + (size_t)(nt * 64 + jt * 16 + fr) * 256 + ks * 32 + fo);
#pragma unroll
            for (int it = 0; it < 4; ++it)
#pragma unroll
                for (int jt = 0; jt < 4; ++jt)
                    acc2[it][jt] = __builtin_amdgcn_mfma_f32_16x16x32_bf16(af[it], bg[jt], acc2[it][jt], 0, 0, 0);
        }
#pragma unroll
        for (int it = 0; it < 4; ++it)
#pragma unroll
            for (int jt = 0; jt < 4; ++jt) {
                const int n = nt * 64 + jt * 16 + fr;
                if (n >= Fq) continue;
                const float mb = mask_b[n];
#pragma unroll
                for (int r = 0; r < 4; ++r) {
                    const int m = m0 + it * 16 + rg * 4 + r;
                    out0[(size_t)m * Fq + n] = x[(size_t)m * Fq + n] * sigf(acc2[it][jt][r] + mb);
                }
            }
    }
}

// ----------------------- fused banded attention (unchanged) -----------------
__global__ __launch_bounds__(256) void band_fused(
    const bf16_t* __restrict__ qsbf, const bf16_t* __restrict__ kbf,
    float* __restrict__ out1, bf16_t* __restrict__ c_att)
{
    __shared__ __align__(16) bf16_t Ks[8 * KW * 32];     // 98304 B, [h/32][j][32]
    __shared__ __align__(16) bf16_t P[6 * 64 * PLD];     // 30720 B
    __shared__ __align__(16) bf16_t KT[256 * KTLD];      // 20480 B

    const int b = blockIdx.y;
    const int t0 = blockIdx.x * 64;
    const int u0 = t0 - 128;
    const int tid = threadIdx.x, lane = tid & 63, w = tid >> 6;
    const int fr = lane & 15, rg = lane >> 4, fo = rg * 8;
    const size_t kbase = (size_t)b * Tq;

#pragma unroll
    for (int it = 0; it < 24; ++it) {
        const int idx = it * 256 + tid;
        const int n  = idx >> 5;
        const int c8 = (idx & 31) * 8;
        uint4 v = {0, 0, 0, 0};
        const int u = u0 + n;
        if (u >= 0) v = *(const uint4*)(kbf + (kbase + u) * (size_t)Hq + c8);
        *(uint4*)&Ks[((c8 >> 5) * KW + n) * 32 + (c8 & 31)] = v;
    }
    __syncthreads();

    f32x4 acc[12] = {};
    const bf16_t* qrow = qsbf + (kbase + t0 + 16 * w + fr) * (size_t)Hq;
#pragma unroll
    for (int ks = 0; ks < 8; ++ks) {
        const bf16x8 aq = *(const bf16x8*)(qrow + ks * 32 + fo);
#pragma unroll
        for (int jf = 0; jf < 12; ++jf) {
            const bf16x8 bk = *(const bf16x8*)&Ks[(ks * KW + jf * 16 + fr) * 32 + fo];
            acc[jf] = __builtin_amdgcn_mfma_f32_16x16x32_bf16(aq, bk, acc[jf], 0, 0, 0);
        }
    }

    const int jmin = (128 - t0) > 0 ? (128 - t0) : 0;
    float mx[4] = {-3e38f, -3e38f, -3e38f, -3e38f};
#pragma unroll
    for (int jf = 0; jf < 12; ++jf)
#pragma unroll
        for (int r = 0; r < 4; ++r) {
            const int i = 16 * w + rg * 4 + r;
            const int j = jf * 16 + fr;
            if (j >= i && j <= i + 128 && j >= jmin)
                mx[r] = fmaxf(mx[r], acc[jf][r]);
        }
#pragma unroll
    for (int d = 1; d < 16; d <<= 1)
#pragma unroll
        for (int r = 0; r < 4; ++r) mx[r] = fmaxf(mx[r], __shfl_xor(mx[r], d));

    float ex[12][4];
    float sm[4] = {0.0f, 0.0f, 0.0f, 0.0f};
#pragma unroll
    for (int jf = 0; jf < 12; ++jf)
#pragma unroll
        for (int r = 0; r < 4; ++r) {
            const int i = 16 * w + rg * 4 + r;
            const int j = jf * 16 + fr;
            const bool v = (j >= i && j <= i + 128 && j >= jmin);
            const float e = v ? __expf(acc[jf][r] - mx[r]) : 0.0f;
            ex[jf][r] = e;
            sm[r] += e;
        }
#pragma unroll
    for (int d = 1; d < 16; d <<= 1)
#pragma unroll
        for (int r = 0; r < 4; ++r) sm[r] += __shfl_xor(sm[r], d);
    float inv[4];
#pragma unroll
    for (int r = 0; r < 4; ++r) inv[r] = 1.0f / (sm[r] + 1e-10f);

#pragma unroll
    for (int jf = 0; jf < 12; ++jf)
#pragma unroll
        for (int r = 0; r < 4; ++r) {
            const int i = 16 * w + rg * 4 + r;
            const int j = jf * 16 + fr;
            const float wv = ex[jf][r] * inv[r];
            if (u0 + j >= 0)
                out1[(kbase + t0 + i) * (size_t)Tq + (u0 + j)] = wv;
            P[((j >> 5) * 64 + i) * PLD + (j & 31)] = (bf16_t)wv;
        }

    {
        const int c4l = (u0 > 0 ? u0 : 0) >> 2;
        const int c4r = (u0 + KW) >> 2;
        const float4 z4 = {0.0f, 0.0f, 0.0f, 0.0f};
        for (int rr = 0; rr < 16; ++rr) {
            float* rowp = out1 + (kbase + t0 + 16 * w + rr) * (size_t)Tq;
            for (int c4 = lane; c4 < c4l; c4 += 64)
                *(float4*)(rowp + 4 * c4) = z4;
            for (int c4 = c4r + lane; c4 < Tq / 4; c4 += 64)
                *(float4*)(rowp + 4 * c4) = z4;
        }
    }

    f32x4 cacc[16] = {};
    for (int jc = 0; jc < 6; ++jc) {
        __syncthreads();
#pragma unroll
        for (int it = 0; it < 4; ++it) {
            const int idx = it * 256 + tid;
            const int jl = idx >> 5;
            const int hc = (idx & 31) * 8;
            const bf16x8 kv = *(const bf16x8*)&Ks[((hc >> 5) * KW + jc * 32 + jl) * 32 + (hc & 31)];
#pragma unroll
            for (int e = 0; e < 8; ++e) KT[(hc + e) * KTLD + jl] = kv[e];
        }
        __syncthreads();
        const bf16x8 pa = *(const bf16x8*)&P[(jc * 64 + 16 * w + fr) * PLD + fo];
#pragma unroll
        for (int hf = 0; hf < 16; ++hf) {
            const bf16x8 bk = *(const bf16x8*)&KT[(hf * 16 + fr) * KTLD + fo];
            cacc[hf] = __builtin_amdgcn_mfma_f32_16x16x32_bf16(pa, bk, cacc[hf], 0, 0, 0);
        }
    }

#pragma unroll
    for (int hf = 0; hf < 16; ++hf)
#pragma unroll
        for (int r = 0; r < 4; ++r) {
            const int i = 16 * w + rg * 4 + r;
            c_att[(kbase + t0 + i) * (size_t)Hq + hf * 16 + fr] = (bf16_t)cacc[hf][r];
        }
}

// ---------------------------------------------------------------------------
extern "C" void kernel_launch(void* const* d_in, const int* in_sizes, int n_in,
                              void* d_out, int out_size, void* d_ws, size_t ws_size,
                              hipStream_t stream)
{
    (void)in_sizes; (void)n_in; (void)out_size; (void)ws_size;
    const float* x        = (const float*)d_in[0];
    const float* feat_w   = (const float*)d_in[1];
    const float* feat_b   = (const float*)d_in[2];
    const float* k_Wih    = (const float*)d_in[3];
    const float* k_Whh    = (const float*)d_in[4];
    const float* k_bih    = (const float*)d_in[5];
    const float* k_bhh    = (const float*)d_in[6];
    const float* q_Wih    = (const float*)d_in[7];
    const float* q_Whh    = (const float*)d_in[8];
    const float* q_bih    = (const float*)d_in[9];
    const float* q_bhh    = (const float*)d_in[10];
    const float* score_w  = (const float*)d_in[11];
    const float* enhance_w= (const float*)d_in[12];
    const float* enhance_b= (const float*)d_in[13];
    const float* mask_w   = (const float*)d_in[14];
    const float* mask_b   = (const float*)d_in[15];

    float* out0 = (float*)d_out;                         // (8,2048,257)
    float* out1 = out0 + (size_t)Bq * Tq * Fq;           // (8,2048,2048)

    // ---- workspace (no fills needed; every word written before read) ----
    float* cst      = (float*)d_ws;                      // 2*TH f32 (c states)
    float* bias_all = cst + (size_t)2 * TH;              // 2048 f32
    bf16_t* cvd = (bf16_t*)(bias_all + 2048);
    bf16_t* xbf     = cvd;                               // reused as qsbf later
    bf16_t* featw   = cvd + CV_O1;
    bf16_t* Wall    = cvd + CV_O2;                       // 2048 rows x 512 [k;q]
    bf16_t* scw     = cvd + CV_O4;
    bf16_t* enw     = cvd + CV_O5;
    bf16_t* mkw     = cvd + CV_O6;
    bf16_t* hfeatbf = cvd + CV_TOT;                      // Mq*256
    bf16_t* hkbf    = hfeatbf + (size_t)Mq * Hq;         // 8*TH
    bf16_t* hqbf    = hkbf + (size_t)Bq * TH;            // 8*TH
    bf16_t* cattb   = hqbf + (size_t)Bq * TH;            // Mq*256

    // 0) conversions + bias fold (one dispatch)
    cvt_all<<<CVB + 1, 256, 0, stream>>>(
        x, feat_w, k_Wih, k_Whh, q_Wih, q_Whh, score_w, enhance_w, mask_w, cvd,
        k_bih, k_bhh, q_bih, q_bhh, bias_all);

    // 1) feat: hfeatbf = tanh(x @ feat_w^T + feat_b)   grid (2, 256)
    gemm_mfma<1, false, true, false><<<dim3(2, Mq / 64), 256, 0, stream>>>(
        xbf, 288, 288, nullptr, 0, 0, featw, feat_b, nullptr, 0,
        nullptr, hfeatbf, Hq, 1 << 30);

    // 2) LSTM k & q: 8 fused steps (K=512, BK=64; b=0 writes c without reading)
    lstm_step<true><<<dim3(8, Tq / 64, 2), 256, 0, stream>>>(
        hfeatbf, nullptr, nullptr, Wall, bias_all, cst, hkbf, hqbf);
    for (int b = 1; b < Bq; ++b)
        lstm_step<false><<<dim3(8, Tq / 64, 2), 256, 0, stream>>>(
            hfeatbf + (size_t)b * TH,
            hkbf + (size_t)(b - 1) * TH, hqbf + (size_t)(b - 1) * TH,
            Wall, bias_all, cst,
            hkbf + (size_t)b * TH, hqbf + (size_t)b * TH);

    // 3) score: qsbf = q @ score_w^T  (bf16, reuses xbf)  grid (2, 256)
    bf16_t* qsbf = xbf;
    gemm_mfma<0, false, true, false><<<dim3(2, Mq / 64), 256, 0, stream>>>(
        hqbf, Hq, Hq, nullptr, 0, 0, scw, nullptr, nullptr, 0,
        nullptr, qsbf, Hq, 1 << 30);

    // 4+5) fused banded softmax + PV; writes full out1 rows
    band_fused<<<dim3(Tq / 64, Bq), 256, 0, stream>>>(qsbf, hkbf, out1, cattb);

    // 6+7) fused enhance + mask: out0 = x * sig(tanh([c,q]@enw+b) @ mkw + mb)
    enmask<<<Mq / 64, 256, 0, stream>>>(
        cattb, hqbf, enw, enhance_b, mkw, mask_b, x, out0);
}

// Round 17
// 215.166 us; speedup vs baseline: 1.6339x; 1.6300x over previous
//
#include <hip/hip_runtime.h>
#include <math.h>

// ---------------------------------------------------------------------------
// AttentionModel on MI355X. Round 17 (base = round 8, 210us, full revert of R16):
//  - score GEMM fused into band_fused phase-0 (qs tile computed per block,
//    stored in LDS aliasing P/KT; one dispatch + 8.4MB x2 traffic deleted).
//  - lstm_step: c-state prefetched into registers before the K-loop (epilogue
//    c-load latency hidden under MFMA).
// ---------------------------------------------------------------------------

#define Bq 8
#define Tq 2048
#define Fq 257
#define Hq 256
#define TH (Tq*Hq)       // 524288
#define KW 192           // k-window rows per 64-row t-tile
#define PLD 40           // P row stride (bf16)
#define KTLD 40          // KT row stride (bf16)
#define QLD 264          // qs LDS row stride (bf16)
#define Mq (Bq*Tq)       // 16384

typedef __bf16 bf16_t;
typedef __bf16 bf16x8 __attribute__((ext_vector_type(8)));
typedef float f32x4 __attribute__((ext_vector_type(4)));

__device__ __forceinline__ float sigf(float x) { return 1.0f / (1.0f + __expf(-x)); }
__device__ __forceinline__ float tanh_f(float x) { return 1.0f - 2.0f / (__expf(2.0f * x) + 1.0f); }

// ------------------- batched fp32 -> bf16 convert + bias fold ---------------
#define CV_X   (Mq*288)            // x padded 257->288
#define CV_FW  (256*288)           // feat_w padded
#define CV_WK  (1024*512)          // [k_Wih | k_Whh]  rows g*256+j
#define CV_WQ  (1024*512)          // [q_Wih | q_Whh]
#define CV_SC  (256*256)
#define CV_EN  (256*512)
#define CV_MK  (384*256)           // mask_w padded rows 257->384
#define CV_O1  CV_X
#define CV_O2  (CV_O1+CV_FW)
#define CV_O3  (CV_O2+CV_WK)
#define CV_O4  (CV_O3+CV_WQ)
#define CV_O5  (CV_O4+CV_SC)
#define CV_O6  (CV_O5+CV_EN)
#define CV_TOT (CV_O6+CV_MK)       // 6,135,808 = 2996 * 2048
#define CVB    (CV_TOT/8/256)      // 2996 data blocks; block CVB = bias fold

__global__ __launch_bounds__(256) void cvt_all(
    const float* __restrict__ x, const float* __restrict__ feat_w,
    const float* __restrict__ kWih, const float* __restrict__ kWhh,
    const float* __restrict__ qWih, const float* __restrict__ qWhh,
    const float* __restrict__ scorew, const float* __restrict__ enhw,
    const float* __restrict__ maskw, bf16_t* __restrict__ dst,
    const float* __restrict__ kbih, const float* __restrict__ kbhh,
    const float* __restrict__ qbih, const float* __restrict__ qbhh,
    float* __restrict__ bias_all)
{
    if (blockIdx.x == CVB) {       // bias fold: 2048 f32
        const int i0 = threadIdx.x * 8;
#pragma unroll
        for (int e = 0; e < 8; ++e) {
            const int i = i0 + e;
            bias_all[i] = (i < 1024) ? kbih[i] + kbhh[i]
                                     : qbih[i - 1024] + qbhh[i - 1024];
        }
        return;
    }
    const int base = (blockIdx.x * 256 + threadIdx.x) * 8;
    bf16_t v[8];
#pragma unroll
    for (int e = 0; e < 8; ++e) {
        const int i = base + e;
        float f;
        if (i < CV_O1)      { const int r = i / 288, c = i - r * 288;
                              f = (c < Fq) ? x[(size_t)r * Fq + c] : 0.0f; }
        else if (i < CV_O2) { const int i2 = i - CV_O1, r = i2 / 288, c = i2 - r * 288;
                              f = (c < Fq) ? feat_w[r * Fq + c] : 0.0f; }
        else if (i < CV_O3) { const int i2 = i - CV_O2, r = i2 >> 9, c = i2 & 511;
                              f = (c < 256) ? kWih[r * 256 + c] : kWhh[r * 256 + c - 256]; }
        else if (i < CV_O4) { const int i2 = i - CV_O3, r = i2 >> 9, c = i2 & 511;
                              f = (c < 256) ? qWih[r * 256 + c] : qWhh[r * 256 + c - 256]; }
        else if (i < CV_O5) { f = scorew[i - CV_O4]; }
        else if (i < CV_O6) { f = enhw[i - CV_O5]; }
        else                { const int i2 = i - CV_O6, r = i2 >> 8, c = i2 & 255;
                              f = (r < Fq) ? maskw[r * 256 + c] : 0.0f; }
        v[e] = (bf16_t)f;
    }
    *(bf16x8*)(dst + base) = *(bf16x8*)v;
}

// ---------------- bf16 MFMA NT GEMM, 64x128 tile (round-8 proven) -----------
__device__ __forceinline__ const bf16_t* seg_ptr(
    const bf16_t* __restrict__ A1, int lda1, int K1,
    const bf16_t* __restrict__ A2, int lda2, int row, int k, int col8)
{
    return (k < K1) ? A1 + (size_t)row * lda1 + k + col8
                    : A2 + (size_t)row * lda2 + (k - K1) + col8;
}

template<int ACT, bool MULX, bool BF16OUT, bool F32OUT>
__global__ __launch_bounds__(256) void gemm_mfma(
    const bf16_t* __restrict__ A1, int lda1, int K1,
    const bf16_t* __restrict__ A2, int lda2, int K2,
    const bf16_t* __restrict__ W,
    const float* __restrict__ bias,
    const float* __restrict__ xm, int ldx,
    float* __restrict__ out, bf16_t* __restrict__ outbf, int ldo, int Nlog)
{
    __shared__ __align__(16) bf16_t As[64 * 32];     // 4 KB
    __shared__ __align__(16) bf16_t Ws[128 * 32];    // 8 KB
    const int tid = threadIdx.x;
    const int lane = tid & 63;
    const int wave = tid >> 6;
    const int wr = wave >> 1, wc = wave & 1;
    const int fr = lane & 15;
    const int fo = (lane >> 4) * 8;
    const int srow = tid >> 2;
    const int scol = (tid & 3) * 8;
    const int m0 = blockIdx.y * 64, n0 = blockIdx.x * 128;

    const int K = K1 + K2;
    const int ldw = K;

    uint4 ar = *(const uint4*)seg_ptr(A1, lda1, K1, A2, lda2, m0 + srow, 0, scol);
    uint4 w0 = *(const uint4*)(W + (size_t)(n0 + srow)      * ldw + scol);
    uint4 w1 = *(const uint4*)(W + (size_t)(n0 + srow + 64) * ldw + scol);

    f32x4 acc[2][4] = {};
    for (int k0 = 0; k0 < K; k0 += 32) {
        __syncthreads();                // prior LDS reads done
        *(uint4*)&As[srow * 32 + scol]        = ar;
        *(uint4*)&Ws[srow * 32 + scol]        = w0;
        *(uint4*)&Ws[(srow + 64) * 32 + scol] = w1;
        if (k0 + 32 < K) {              // prefetch k+1 (hides under MFMA below)
            ar = *(const uint4*)seg_ptr(A1, lda1, K1, A2, lda2, m0 + srow, k0 + 32, scol);
            w0 = *(const uint4*)(W + (size_t)(n0 + srow)      * ldw + k0 + 32 + scol);
            w1 = *(const uint4*)(W + (size_t)(n0 + srow + 64) * ldw + k0 + 32 + scol);
        }
        __syncthreads();
        bf16x8 af[2], bfr[4];
#pragma unroll
        for (int i = 0; i < 2; ++i) af[i]  = *(const bf16x8*)&As[(wr * 32 + i * 16 + fr) * 32 + fo];
#pragma unroll
        for (int j = 0; j < 4; ++j) bfr[j] = *(const bf16x8*)&Ws[(wc * 64 + j * 16 + fr) * 32 + fo];
#pragma unroll
        for (int i = 0; i < 2; ++i)
#pragma unroll
            for (int j = 0; j < 4; ++j)
                acc[i][j] = __builtin_amdgcn_mfma_f32_16x16x32_bf16(af[i], bfr[j], acc[i][j], 0, 0, 0);
    }

    const int rbase = (lane >> 4) * 4;
#pragma unroll
    for (int i = 0; i < 2; ++i) {
#pragma unroll
        for (int j = 0; j < 4; ++j) {
            const int n = n0 + wc * 64 + j * 16 + fr;
            if (n >= Nlog) continue;
            const float bv = bias ? bias[n] : 0.0f;
            const int m = m0 + wr * 32 + i * 16 + rbase;
#pragma unroll
            for (int r = 0; r < 4; ++r) {
                float v = acc[i][j][r] + bv;
                if (ACT == 1) v = tanh_f(v);
                else if (ACT == 2) v = sigf(v);
                if (MULX) v *= xm[(size_t)(m + r) * ldx + n];
                if (F32OUT) out[(size_t)(m + r) * ldo + n] = v;
                if (BF16OUT) outbf[(size_t)(m + r) * ldo + n] = (bf16_t)v;
            }
        }
    }
}

// -------- LSTM step: gates = hfeat@Wih^T + hprev@Whh^T + bias, cell fused ----
// 64 rows x (32 j x 4 gates) per block; grid (8, 32, 2) = 512 blocks.
// Round-8 proven schedule + c prefetched into registers before the K-loop.
// FIRST: c_prev = 0 -> no c read, K=256.
template<bool FIRST>
__global__ __launch_bounds__(256) void lstm_step(
    const bf16_t* __restrict__ hfb,                                   // hfeat + b*TH
    const bf16_t* __restrict__ hkp, const bf16_t* __restrict__ hqp,   // prev h
    const bf16_t* __restrict__ Wall, const float* __restrict__ bias_all,
    float* __restrict__ cst,
    bf16_t* __restrict__ hk, bf16_t* __restrict__ hq)
{
    __shared__ __align__(16) bf16_t As[64 * 32];    // 4 KB
    __shared__ __align__(16) bf16_t Ws[128 * 32];   // 8 KB
    const int z = blockIdx.z;
    const bf16_t* hprev = z ? hqp : hkp;
    const bf16_t* Wz = Wall + (size_t)z * (1024 * 512);
    float* c     = cst + (size_t)z * TH;
    bf16_t* hout = z ? hq : hk;

    const int tid = threadIdx.x, lane = tid & 63, wave = tid >> 6;
    const int wr = wave >> 1, wc = wave & 1;
    const int fr = lane & 15, rg = lane >> 4, fo = rg * 8;
    const int m0 = blockIdx.y * 64;
    const int jb = blockIdx.x * 32;

    const int s0 = tid >> 2, acol = (tid & 3) * 8;
    const int s1 = s0 + 64;
    const int wn0 = ((s0 >> 5) * 256) + jb + (s0 & 31);   // gate-major strips
    const int wn1 = ((s1 >> 5) * 256) + jb + (s1 & 31);

    constexpr int NIT = FIRST ? 8 : 16;   // K = 256 (Wih only) or 512

    // epilogue indices + c/bias prefetch (latency hidden under K-loop)
    const int j = jb + wc * 16 + fr;
    float bs[4];
#pragma unroll
    for (int g = 0; g < 4; ++g) bs[g] = bias_all[z * 1024 + g * 256 + j];
    float cpre[2][4];
    if (!FIRST) {
#pragma unroll
        for (int i = 0; i < 2; ++i)
#pragma unroll
            for (int r = 0; r < 4; ++r)
                cpre[i][r] = c[(size_t)(m0 + wr * 32 + i * 16 + rg * 4 + r) * Hq + j];
    }

    uint4 ar  = *(const uint4*)(hfb + (size_t)(m0 + s0) * Hq + acol);
    uint4 w0r = *(const uint4*)(Wz + (size_t)wn0 * 512 + acol);
    uint4 w1r = *(const uint4*)(Wz + (size_t)wn1 * 512 + acol);

    f32x4 acc[2][4] = {};
#pragma unroll
    for (int t = 0; t < NIT; ++t) {
        if (t) __syncthreads();                  // prior LDS reads done
        *(uint4*)&As[s0 * 32 + acol] = ar;
        *(uint4*)&Ws[s0 * 32 + acol] = w0r;
        *(uint4*)&Ws[s1 * 32 + acol] = w1r;
        if (t + 1 < NIT) {                       // prefetch next k-slice
            const int tn = t + 1;
            ar  = (tn < 8)
                ? *(const uint4*)(hfb   + (size_t)(m0 + s0) * Hq + tn * 32 + acol)
                : *(const uint4*)(hprev + (size_t)(m0 + s0) * Hq + (tn - 8) * 32 + acol);
            w0r = *(const uint4*)(Wz + (size_t)wn0 * 512 + tn * 32 + acol);
            w1r = *(const uint4*)(Wz + (size_t)wn1 * 512 + tn * 32 + acol);
        }
        __syncthreads();
        bf16x8 af[2], bg[4];
#pragma unroll
        for (int i = 0; i < 2; ++i) af[i] = *(const bf16x8*)&As[(wr * 32 + i * 16 + fr) * 32 + fo];
#pragma unroll
        for (int g = 0; g < 4; ++g) bg[g] = *(const bf16x8*)&Ws[(g * 32 + wc * 16 + fr) * 32 + fo];
#pragma unroll
        for (int i = 0; i < 2; ++i)
#pragma unroll
            for (int g = 0; g < 4; ++g)
                acc[i][g] = __builtin_amdgcn_mfma_f32_16x16x32_bf16(af[i], bg[g], acc[i][g], 0, 0, 0);
    }

    // cell epilogue: thread owns 4 gates of column j for 8 rows
#pragma unroll
    for (int i = 0; i < 2; ++i)
#pragma unroll
        for (int r = 0; r < 4; ++r) {
            const int t = m0 + wr * 32 + i * 16 + rg * 4 + r;
            const size_t ix = (size_t)t * Hq + j;
            const float gi = acc[i][0][r] + bs[0];
            const float gf = acc[i][1][r] + bs[1];
            const float gg = acc[i][2][r] + bs[2];
            const float go = acc[i][3][r] + bs[3];
            const float cn = FIRST ? sigf(gi) * tanh_f(gg)
                                   : sigf(gf) * cpre[i][r] + sigf(gi) * tanh_f(gg);
            c[ix] = cn;
            hout[ix] = (bf16_t)(sigf(go) * tanh_f(cn));
        }
}

// ------------- fused banded attention with phase-0 score GEMM ---------------
// Per block: batch b, 64 t-rows. Phase 0: qs = q @ score_w^T for this tile
// (B-frags from L2; qs bf16 -> LDS aliasing P/KT). Then K-window staging,
// QK^T, exact band softmax, w -> out1 + P, PV with K transpose.
__global__ __launch_bounds__(256) void band_fused(
    const bf16_t* __restrict__ hqbf, const bf16_t* __restrict__ scw,
    const bf16_t* __restrict__ kbf,
    float* __restrict__ out1, bf16_t* __restrict__ c_att)
{
    __shared__ __align__(16) bf16_t Ks[8 * KW * 32];               // 98304 B
    __shared__ __align__(16) bf16_t Puni[6 * 64 * PLD + 256 * KTLD]; // 51200 B
    bf16_t* const P   = Puni;                    // softmax weights (bf16)
    bf16_t* const KT  = Puni + 6 * 64 * PLD;     // PV transpose scratch
    bf16_t* const qsS = Puni;                    // phase-0 qs tile (dead before P)

    const int b = blockIdx.y;
    const int t0 = blockIdx.x * 64;
    const int u0 = t0 - 128;
    const int tid = threadIdx.x, lane = tid & 63, w = tid >> 6;
    const int fr = lane & 15, rg = lane >> 4, fo = rg * 8;
    const size_t kbase = (size_t)b * Tq;

    // ---- stage K window rows u0 .. u0+191 (coalesced; zeros for u<0) ----
#pragma unroll
    for (int it = 0; it < 24; ++it) {
        const int idx = it * 256 + tid;
        const int n  = idx >> 5;
        const int c8 = (idx & 31) * 8;
        uint4 v = {0, 0, 0, 0};
        const int u = u0 + n;
        if (u >= 0) v = *(const uint4*)(kbf + (kbase + u) * (size_t)Hq + c8);
        *(uint4*)&Ks[((c8 >> 5) * KW + n) * 32 + (c8 & 31)] = v;
    }

    // ---- phase 0: qs rows for this block (wave w owns rows 16w..16w+15) ----
    {
        f32x4 sacc[16] = {};
        const bf16_t* qrow = hqbf + (kbase + t0 + 16 * w + fr) * (size_t)Hq;
#pragma unroll
        for (int ks = 0; ks < 8; ++ks) {
            const bf16x8 aq = *(const bf16x8*)(qrow + ks * 32 + fo);
#pragma unroll
            for (int nf = 0; nf < 16; ++nf) {
                const bf16x8 bsw = *(const bf16x8*)(scw + (size_t)(nf * 16 + fr) * 256 + ks * 32 + fo);
                sacc[nf] = __builtin_amdgcn_mfma_f32_16x16x32_bf16(aq, bsw, sacc[nf], 0, 0, 0);
            }
        }
        // D layout: col = nf*16 + (lane&15), row = 16w + (lane>>4)*4 + r
#pragma unroll
        for (int nf = 0; nf < 16; ++nf)
#pragma unroll
            for (int r = 0; r < 4; ++r)
                qsS[(16 * w + rg * 4 + r) * QLD + nf * 16 + fr] = (bf16_t)sacc[nf][r];
    }
    __syncthreads();     // Ks staged + qsS visible

    // ---- QK^T: S[i][j], A-frags from qsS ----
    f32x4 acc[12] = {};
#pragma unroll
    for (int ks = 0; ks < 8; ++ks) {
        const bf16x8 aq = *(const bf16x8*)&qsS[(16 * w + fr) * QLD + ks * 32 + fo];
#pragma unroll
        for (int jf = 0; jf < 12; ++jf) {
            const bf16x8 bk = *(const bf16x8*)&Ks[(ks * KW + jf * 16 + fr) * 32 + fo];
            acc[jf] = __builtin_amdgcn_mfma_f32_16x16x32_bf16(aq, bk, acc[jf], 0, 0, 0);
        }
    }
    __syncthreads();     // all waves done reading qsS before P overwrites it

    // ---- band softmax (exact) ----
    const int jmin = (128 - t0) > 0 ? (128 - t0) : 0;
    float mx[4] = {-3e38f, -3e38f, -3e38f, -3e38f};
#pragma unroll
    for (int jf = 0; jf < 12; ++jf)
#pragma unroll
        for (int r = 0; r < 4; ++r) {
            const int i = 16 * w + rg * 4 + r;
            const int j = jf * 16 + fr;
            if (j >= i && j <= i + 128 && j >= jmin)
                mx[r] = fmaxf(mx[r], acc[jf][r]);
        }
#pragma unroll
    for (int d = 1; d < 16; d <<= 1)
#pragma unroll
        for (int r = 0; r < 4; ++r) mx[r] = fmaxf(mx[r], __shfl_xor(mx[r], d));

    float ex[12][4];
    float sm[4] = {0.0f, 0.0f, 0.0f, 0.0f};
#pragma unroll
    for (int jf = 0; jf < 12; ++jf)
#pragma unroll
        for (int r = 0; r < 4; ++r) {
            const int i = 16 * w + rg * 4 + r;
            const int j = jf * 16 + fr;
            const bool v = (j >= i && j <= i + 128 && j >= jmin);
            const float e = v ? __expf(acc[jf][r] - mx[r]) : 0.0f;
            ex[jf][r] = e;
            sm[r] += e;
        }
#pragma unroll
    for (int d = 1; d < 16; d <<= 1)
#pragma unroll
        for (int r = 0; r < 4; ++r) sm[r] += __shfl_xor(sm[r], d);
    float inv[4];
#pragma unroll
    for (int r = 0; r < 4; ++r) inv[r] = 1.0f / (sm[r] + 1e-10f);

    // ---- band values -> out1 (f32) + P (bf16 LDS) ----
#pragma unroll
    for (int jf = 0; jf < 12; ++jf)
#pragma unroll
        for (int r = 0; r < 4; ++r) {
            const int i = 16 * w + rg * 4 + r;
            const int j = jf * 16 + fr;
            const float wv = ex[jf][r] * inv[r];
            if (u0 + j >= 0)
                out1[(kbase + t0 + i) * (size_t)Tq + (u0 + j)] = wv;
            P[((j >> 5) * 64 + i) * PLD + (j & 31)] = (bf16_t)wv;
        }

    // ---- zero-fill out1 outside the window ----
    {
        const int c4l = (u0 > 0 ? u0 : 0) >> 2;
        const int c4r = (u0 + KW) >> 2;
        const float4 z4 = {0.0f, 0.0f, 0.0f, 0.0f};
        for (int rr = 0; rr < 16; ++rr) {
            float* rowp = out1 + (kbase + t0 + 16 * w + rr) * (size_t)Tq;
            for (int c4 = lane; c4 < c4l; c4 += 64)
                *(float4*)(rowp + 4 * c4) = z4;
            for (int c4 = c4r + lane; c4 < Tq / 4; c4 += 64)
                *(float4*)(rowp + 4 * c4) = z4;
        }
    }

    // ---- PV with per-32-j LDS transpose of K ----
    f32x4 cacc[16] = {};
    for (int jc = 0; jc < 6; ++jc) {
        __syncthreads();
#pragma unroll
        for (int it = 0; it < 4; ++it) {
            const int idx = it * 256 + tid;
            const int jl = idx >> 5;
            const int hc = (idx & 31) * 8;
            const bf16x8 kv = *(const bf16x8*)&Ks[((hc >> 5) * KW + jc * 32 + jl) * 32 + (hc & 31)];
#pragma unroll
            for (int e = 0; e < 8; ++e) KT[(hc + e) * KTLD + jl] = kv[e];
        }
        __syncthreads();
        const bf16x8 pa = *(const bf16x8*)&P[(jc * 64 + 16 * w + fr) * PLD + fo];
#pragma unroll
        for (int hf = 0; hf < 16; ++hf) {
            const bf16x8 bk = *(const bf16x8*)&KT[(hf * 16 + fr) * KTLD + fo];
            cacc[hf] = __builtin_amdgcn_mfma_f32_16x16x32_bf16(pa, bk, cacc[hf], 0, 0, 0);
        }
    }

#pragma unroll
    for (int hf = 0; hf < 16; ++hf)
#pragma unroll
        for (int r = 0; r < 4; ++r) {
            const int i = 16 * w + rg * 4 + r;
            c_att[(kbase + t0 + i) * (size_t)Hq + hf * 16 + fr] = (bf16_t)cacc[hf][r];
        }
}

// ---------------------------------------------------------------------------
extern "C" void kernel_launch(void* const* d_in, const int* in_sizes, int n_in,
                              void* d_out, int out_size, void* d_ws, size_t ws_size,
                              hipStream_t stream)
{
    (void)in_sizes; (void)n_in; (void)out_size; (void)ws_size;
    const float* x        = (const float*)d_in[0];
    const float* feat_w   = (const float*)d_in[1];
    const float* feat_b   = (const float*)d_in[2];
    const float* k_Wih    = (const float*)d_in[3];
    const float* k_Whh    = (const float*)d_in[4];
    const float* k_bih    = (const float*)d_in[5];
    const float* k_bhh    = (const float*)d_in[6];
    const float* q_Wih    = (const float*)d_in[7];
    const float* q_Whh    = (const float*)d_in[8];
    const float* q_bih    = (const float*)d_in[9];
    const float* q_bhh    = (const float*)d_in[10];
    const float* score_w  = (const float*)d_in[11];
    const float* enhance_w= (const float*)d_in[12];
    const float* enhance_b= (const float*)d_in[13];
    const float* mask_w   = (const float*)d_in[14];
    const float* mask_b   = (const float*)d_in[15];

    float* out0 = (float*)d_out;                         // (8,2048,257)
    float* out1 = out0 + (size_t)Bq * Tq * Fq;           // (8,2048,2048)

    // ---- workspace (no fills needed; every word written before read) ----
    float* cst      = (float*)d_ws;                      // 2*TH f32 (c states)
    float* bias_all = cst + (size_t)2 * TH;              // 2048 f32
    bf16_t* cvd = (bf16_t*)(bias_all + 2048);
    bf16_t* xbf     = cvd;
    bf16_t* featw   = cvd + CV_O1;
    bf16_t* Wall    = cvd + CV_O2;                       // 2048 rows x 512 [k;q]
    bf16_t* scw     = cvd + CV_O4;
    bf16_t* enw     = cvd + CV_O5;
    bf16_t* mkw     = cvd + CV_O6;
    bf16_t* hfeatbf = cvd + CV_TOT;                      // Mq*256 (reused as out_h)
    bf16_t* hkbf    = hfeatbf + (size_t)Mq * Hq;         // 8*TH
    bf16_t* hqbf    = hkbf + (size_t)Bq * TH;            // 8*TH
    bf16_t* cattb   = hqbf + (size_t)Bq * TH;            // Mq*256

    // 0) conversions + bias fold (one dispatch)
    cvt_all<<<CVB + 1, 256, 0, stream>>>(
        x, feat_w, k_Wih, k_Whh, q_Wih, q_Whh, score_w, enhance_w, mask_w, cvd,
        k_bih, k_bhh, q_bih, q_bhh, bias_all);

    // 1) feat: hfeatbf = tanh(x @ feat_w^T + feat_b)   grid (2, 256)
    gemm_mfma<1, false, true, false><<<dim3(2, Mq / 64), 256, 0, stream>>>(
        xbf, 288, 288, nullptr, 0, 0, featw, feat_b, nullptr, 0,
        nullptr, hfeatbf, Hq, 1 << 30);

    // 2) LSTM k & q: 8 fused steps (K=512; b=0 writes c without reading)
    lstm_step<true><<<dim3(8, Tq / 64, 2), 256, 0, stream>>>(
        hfeatbf, nullptr, nullptr, Wall, bias_all, cst, hkbf, hqbf);
    for (int b = 1; b < Bq; ++b)
        lstm_step<false><<<dim3(8, Tq / 64, 2), 256, 0, stream>>>(
            hfeatbf + (size_t)b * TH,
            hkbf + (size_t)(b - 1) * TH, hqbf + (size_t)(b - 1) * TH,
            Wall, bias_all, cst,
            hkbf + (size_t)b * TH, hqbf + (size_t)b * TH);

    // 3+4+5) fused score + banded softmax + PV; writes full out1 rows
    band_fused<<<dim3(Tq / 64, Bq), 256, 0, stream>>>(hqbf, scw, hkbf, out1, cattb);

    // 6) enhance: out_h = tanh([c, q] @ enhance_w^T + b)  grid (2, 256)
    bf16_t* outh = hfeatbf;
    gemm_mfma<1, false, true, false><<<dim3(2, Mq / 64), 256, 0, stream>>>(
        cattb, Hq, Hq, hqbf, Hq, Hq, enw, enhance_b, nullptr, 0,
        nullptr, outh, Hq, 1 << 30);

    // 7) mask + final: out0 = x * sigmoid(out_h @ mask_w^T + mask_b)  grid (3, 256)
    gemm_mfma<2, true, false, true><<<dim3(3, Mq / 64), 256, 0, stream>>>(
        outh, Hq, Hq, nullptr, 0, 0, mkw, mask_b, x, Fq,
        out0, nullptr, Fq, Fq);
}

// Round 18
// 209.975 us; speedup vs baseline: 1.6743x; 1.0247x over previous
//
#include <hip/hip_runtime.h>
#include <math.h>

// ---------------------------------------------------------------------------
// AttentionModel on MI355X. Round 18 (base = round 8, 210us, R17 extras dropped):
//  - out1 zero-fill (119 MB) moved from BW-saturated band_fused into the 8
//    latency-bound lstm_steps (step b zeros batch b). Stores issued AFTER each
//    iter's prefetch loads -> load waits stay counted (vmcnt>0), stores drain
//    under the K-loop instead of stalling anything.
//  - band_fused writes only the clamped 192-col band windows.
// ---------------------------------------------------------------------------

#define Bq 8
#define Tq 2048
#define Fq 257
#define Hq 256
#define TH (Tq*Hq)       // 524288
#define KW 192           // k-window rows per 64-row t-tile
#define PLD 40           // P row stride (bf16)
#define KTLD 40          // KT row stride (bf16)
#define Mq (Bq*Tq)       // 16384

typedef __bf16 bf16_t;
typedef __bf16 bf16x8 __attribute__((ext_vector_type(8)));
typedef float f32x4 __attribute__((ext_vector_type(4)));

__device__ __forceinline__ float sigf(float x) { return 1.0f / (1.0f + __expf(-x)); }
__device__ __forceinline__ float tanh_f(float x) { return 1.0f - 2.0f / (__expf(2.0f * x) + 1.0f); }

// ------------------- batched fp32 -> bf16 convert + bias fold ---------------
#define CV_X   (Mq*288)            // x padded 257->288
#define CV_FW  (256*288)           // feat_w padded
#define CV_WK  (1024*512)          // [k_Wih | k_Whh]  rows g*256+j
#define CV_WQ  (1024*512)          // [q_Wih | q_Whh]
#define CV_SC  (256*256)
#define CV_EN  (256*512)
#define CV_MK  (384*256)           // mask_w padded rows 257->384
#define CV_O1  CV_X
#define CV_O2  (CV_O1+CV_FW)
#define CV_O3  (CV_O2+CV_WK)
#define CV_O4  (CV_O3+CV_WQ)
#define CV_O5  (CV_O4+CV_SC)
#define CV_O6  (CV_O5+CV_EN)
#define CV_TOT (CV_O6+CV_MK)       // 6,135,808 = 2996 * 2048
#define CVB    (CV_TOT/8/256)      // 2996 data blocks; block CVB = bias fold

__global__ __launch_bounds__(256) void cvt_all(
    const float* __restrict__ x, const float* __restrict__ feat_w,
    const float* __restrict__ kWih, const float* __restrict__ kWhh,
    const float* __restrict__ qWih, const float* __restrict__ qWhh,
    const float* __restrict__ scorew, const float* __restrict__ enhw,
    const float* __restrict__ maskw, bf16_t* __restrict__ dst,
    const float* __restrict__ kbih, const float* __restrict__ kbhh,
    const float* __restrict__ qbih, const float* __restrict__ qbhh,
    float* __restrict__ bias_all)
{
    if (blockIdx.x == CVB) {       // bias fold: 2048 f32
        const int i0 = threadIdx.x * 8;
#pragma unroll
        for (int e = 0; e < 8; ++e) {
            const int i = i0 + e;
            bias_all[i] = (i < 1024) ? kbih[i] + kbhh[i]
                                     : qbih[i - 1024] + qbhh[i - 1024];
        }
        return;
    }
    const int base = (blockIdx.x * 256 + threadIdx.x) * 8;
    bf16_t v[8];
#pragma unroll
    for (int e = 0; e < 8; ++e) {
        const int i = base + e;
        float f;
        if (i < CV_O1)      { const int r = i / 288, c = i - r * 288;
                              f = (c < Fq) ? x[(size_t)r * Fq + c] : 0.0f; }
        else if (i < CV_O2) { const int i2 = i - CV_O1, r = i2 / 288, c = i2 - r * 288;
                              f = (c < Fq) ? feat_w[r * Fq + c] : 0.0f; }
        else if (i < CV_O3) { const int i2 = i - CV_O2, r = i2 >> 9, c = i2 & 511;
                              f = (c < 256) ? kWih[r * 256 + c] : kWhh[r * 256 + c - 256]; }
        else if (i < CV_O4) { const int i2 = i - CV_O3, r = i2 >> 9, c = i2 & 511;
                              f = (c < 256) ? qWih[r * 256 + c] : qWhh[r * 256 + c - 256]; }
        else if (i < CV_O5) { f = scorew[i - CV_O4]; }
        else if (i < CV_O6) { f = enhw[i - CV_O5]; }
        else                { const int i2 = i - CV_O6, r = i2 >> 8, c = i2 & 255;
                              f = (r < Fq) ? maskw[r * 256 + c] : 0.0f; }
        v[e] = (bf16_t)f;
    }
    *(bf16x8*)(dst + base) = *(bf16x8*)v;
}

// ---------------- bf16 MFMA NT GEMM, 64x128 tile (round-8 proven) -----------
__device__ __forceinline__ const bf16_t* seg_ptr(
    const bf16_t* __restrict__ A1, int lda1, int K1,
    const bf16_t* __restrict__ A2, int lda2, int row, int k, int col8)
{
    return (k < K1) ? A1 + (size_t)row * lda1 + k + col8
                    : A2 + (size_t)row * lda2 + (k - K1) + col8;
}

template<int ACT, bool MULX, bool BF16OUT, bool F32OUT>
__global__ __launch_bounds__(256) void gemm_mfma(
    const bf16_t* __restrict__ A1, int lda1, int K1,
    const bf16_t* __restrict__ A2, int lda2, int K2,
    const bf16_t* __restrict__ W,
    const float* __restrict__ bias,
    const float* __restrict__ xm, int ldx,
    float* __restrict__ out, bf16_t* __restrict__ outbf, int ldo, int Nlog)
{
    __shared__ __align__(16) bf16_t As[64 * 32];     // 4 KB
    __shared__ __align__(16) bf16_t Ws[128 * 32];    // 8 KB
    const int tid = threadIdx.x;
    const int lane = tid & 63;
    const int wave = tid >> 6;
    const int wr = wave >> 1, wc = wave & 1;
    const int fr = lane & 15;
    const int fo = (lane >> 4) * 8;
    const int srow = tid >> 2;
    const int scol = (tid & 3) * 8;
    const int m0 = blockIdx.y * 64, n0 = blockIdx.x * 128;

    const int K = K1 + K2;
    const int ldw = K;

    uint4 ar = *(const uint4*)seg_ptr(A1, lda1, K1, A2, lda2, m0 + srow, 0, scol);
    uint4 w0 = *(const uint4*)(W + (size_t)(n0 + srow)      * ldw + scol);
    uint4 w1 = *(const uint4*)(W + (size_t)(n0 + srow + 64) * ldw + scol);

    f32x4 acc[2][4] = {};
    for (int k0 = 0; k0 < K; k0 += 32) {
        __syncthreads();                // prior LDS reads done
        *(uint4*)&As[srow * 32 + scol]        = ar;
        *(uint4*)&Ws[srow * 32 + scol]        = w0;
        *(uint4*)&Ws[(srow + 64) * 32 + scol] = w1;
        if (k0 + 32 < K) {              // prefetch k+1 (hides under MFMA below)
            ar = *(const uint4*)seg_ptr(A1, lda1, K1, A2, lda2, m0 + srow, k0 + 32, scol);
            w0 = *(const uint4*)(W + (size_t)(n0 + srow)      * ldw + k0 + 32 + scol);
            w1 = *(const uint4*)(W + (size_t)(n0 + srow + 64) * ldw + k0 + 32 + scol);
        }
        __syncthreads();
        bf16x8 af[2], bfr[4];
#pragma unroll
        for (int i = 0; i < 2; ++i) af[i]  = *(const bf16x8*)&As[(wr * 32 + i * 16 + fr) * 32 + fo];
#pragma unroll
        for (int j = 0; j < 4; ++j) bfr[j] = *(const bf16x8*)&Ws[(wc * 64 + j * 16 + fr) * 32 + fo];
#pragma unroll
        for (int i = 0; i < 2; ++i)
#pragma unroll
            for (int j = 0; j < 4; ++j)
                acc[i][j] = __builtin_amdgcn_mfma_f32_16x16x32_bf16(af[i], bfr[j], acc[i][j], 0, 0, 0);
    }

    const int rbase = (lane >> 4) * 4;
#pragma unroll
    for (int i = 0; i < 2; ++i) {
#pragma unroll
        for (int j = 0; j < 4; ++j) {
            const int n = n0 + wc * 64 + j * 16 + fr;
            if (n >= Nlog) continue;
            const float bv = bias ? bias[n] : 0.0f;
            const int m = m0 + wr * 32 + i * 16 + rbase;
#pragma unroll
            for (int r = 0; r < 4; ++r) {
                float v = acc[i][j][r] + bv;
                if (ACT == 1) v = tanh_f(v);
                else if (ACT == 2) v = sigf(v);
                if (MULX) v *= xm[(size_t)(m + r) * ldx + n];
                if (F32OUT) out[(size_t)(m + r) * ldo + n] = v;
                if (BF16OUT) outbf[(size_t)(m + r) * ldo + n] = (bf16_t)v;
            }
        }
    }
}

// -------- LSTM step: gates = hfeat@Wih^T + hprev@Whh^T + bias, cell fused ----
// 64 rows x (32 j x 4 gates) per block; grid (8, 32, 2) = 512 blocks.
// Round-8 proven schedule. Additionally zero-fills this batch's out1 rows
// outside the band window (one float4 chunk per early iter, issued AFTER the
// prefetch loads so load waits stay counted and stores drain under compute).
// FIRST: c_prev = 0 -> no c read, K=256.
template<bool FIRST>
__global__ __launch_bounds__(256) void lstm_step(
    const bf16_t* __restrict__ hfb,                                   // hfeat + b*TH
    const bf16_t* __restrict__ hkp, const bf16_t* __restrict__ hqp,   // prev h
    const bf16_t* __restrict__ Wall, const float* __restrict__ bias_all,
    float* __restrict__ cst,
    bf16_t* __restrict__ hk, bf16_t* __restrict__ hq,
    float* __restrict__ out1_b)                                       // out1 + b*Tq*Tq
{
    __shared__ __align__(16) bf16_t As[64 * 32];    // 4 KB
    __shared__ __align__(16) bf16_t Ws[128 * 32];   // 8 KB
    const int z = blockIdx.z;
    const bf16_t* hprev = z ? hqp : hkp;
    const bf16_t* Wz = Wall + (size_t)z * (1024 * 512);
    float* c     = cst + (size_t)z * TH;
    bf16_t* hout = z ? hq : hk;

    const int tid = threadIdx.x, lane = tid & 63, wave = tid >> 6;
    const int wr = wave >> 1, wc = wave & 1;
    const int fr = lane & 15, rg = lane >> 4, fo = rg * 8;
    const int m0 = blockIdx.y * 64;
    const int jb = blockIdx.x * 32;

    const int s0 = tid >> 2, acol = (tid & 3) * 8;
    const int s1 = s0 + 64;
    const int wn0 = ((s0 >> 5) * 256) + jb + (s0 & 31);   // gate-major strips
    const int wn1 = ((s1 >> 5) * 256) + jb + (s1 & 31);

    constexpr int NIT = FIRST ? 8 : 16;   // K = 256 (Wih only) or 512

    // zero-fill geometry: this block owns 4 out1 rows (all in one 64-tile)
    const int blk = (blockIdx.z << 8) + (blockIdx.y << 3) + blockIdx.x;  // 0..511
    const int r0z = blk << 2;                         // first of 4 rows
    const int u0z = ((r0z >> 6) << 6) - 128;
    const int lc4 = (u0z > 0 ? u0z : 0) >> 2;         // left zeros:  [0, lc4)
    const int rc4 = (u0z + KW) >> 2;                  // right zeros: [rc4, 512)
    const int nzc4 = lc4 + 512 - rc4;                 // zero c4 per row (<=496)

    uint4 ar  = *(const uint4*)(hfb + (size_t)(m0 + s0) * Hq + acol);
    uint4 w0r = *(const uint4*)(Wz + (size_t)wn0 * 512 + acol);
    uint4 w1r = *(const uint4*)(Wz + (size_t)wn1 * 512 + acol);

    f32x4 acc[2][4] = {};
#pragma unroll
    for (int t = 0; t < NIT; ++t) {
        if (t) __syncthreads();                  // prior LDS reads done
        *(uint4*)&As[s0 * 32 + acol] = ar;
        *(uint4*)&Ws[s0 * 32 + acol] = w0r;
        *(uint4*)&Ws[s1 * 32 + acol] = w1r;
        if (t + 1 < NIT) {                       // prefetch next k-slice
            const int tn = t + 1;
            ar  = (tn < 8)
                ? *(const uint4*)(hfb   + (size_t)(m0 + s0) * Hq + tn * 32 + acol)
                : *(const uint4*)(hprev + (size_t)(m0 + s0) * Hq + (tn - 8) * 32 + acol);
            w0r = *(const uint4*)(Wz + (size_t)wn0 * 512 + tn * 32 + acol);
            w1r = *(const uint4*)(Wz + (size_t)wn1 * 512 + tn * 32 + acol);
        }
        if (t < 8) {                             // one zero chunk, AFTER the loads
            const int f = t * 256 + tid;         // 0..2047 over 4 rows x 512 c4
            const int r = f >> 9, p = f & 511;
            if (p < nzc4) {
                const int col4 = (p < lc4) ? p : rc4 + (p - lc4);
                const float4 z4 = {0.0f, 0.0f, 0.0f, 0.0f};
                *(float4*)(out1_b + (size_t)(r0z + r) * Tq + 4 * col4) = z4;
            }
        }
        __syncthreads();
        bf16x8 af[2], bg[4];
#pragma unroll
        for (int i = 0; i < 2; ++i) af[i] = *(const bf16x8*)&As[(wr * 32 + i * 16 + fr) * 32 + fo];
#pragma unroll
        for (int g = 0; g < 4; ++g) bg[g] = *(const bf16x8*)&Ws[(g * 32 + wc * 16 + fr) * 32 + fo];
#pragma unroll
        for (int i = 0; i < 2; ++i)
#pragma unroll
            for (int g = 0; g < 4; ++g)
                acc[i][g] = __builtin_amdgcn_mfma_f32_16x16x32_bf16(af[i], bg[g], acc[i][g], 0, 0, 0);
    }

    // cell epilogue: thread owns 4 gates of column j for 8 rows
    const int j = jb + wc * 16 + fr;
    float bs[4];
#pragma unroll
    for (int g = 0; g < 4; ++g) bs[g] = bias_all[z * 1024 + g * 256 + j];
#pragma unroll
    for (int i = 0; i < 2; ++i)
#pragma unroll
        for (int r = 0; r < 4; ++r) {
            const int t = m0 + wr * 32 + i * 16 + rg * 4 + r;
            const size_t ix = (size_t)t * Hq + j;
            const float gi = acc[i][0][r] + bs[0];
            const float gf = acc[i][1][r] + bs[1];
            const float gg = acc[i][2][r] + bs[2];
            const float go = acc[i][3][r] + bs[3];
            const float cn = FIRST ? sigf(gi) * tanh_f(gg)
                                   : sigf(gf) * c[ix] + sigf(gi) * tanh_f(gg);
            c[ix] = cn;
            hout[ix] = (bf16_t)(sigf(go) * tanh_f(cn));
        }
}

// --------------- fused banded attention (band window writes only) -----------
__global__ __launch_bounds__(256) void band_fused(
    const bf16_t* __restrict__ qsbf, const bf16_t* __restrict__ kbf,
    float* __restrict__ out1, bf16_t* __restrict__ c_att)
{
    __shared__ __align__(16) bf16_t Ks[8 * KW * 32];     // 98304 B, [h/32][j][32]
    __shared__ __align__(16) bf16_t P[6 * 64 * PLD];     // 30720 B
    __shared__ __align__(16) bf16_t KT[256 * KTLD];      // 20480 B

    const int b = blockIdx.y;
    const int t0 = blockIdx.x * 64;
    const int u0 = t0 - 128;
    const int tid = threadIdx.x, lane = tid & 63, w = tid >> 6;
    const int fr = lane & 15, rg = lane >> 4, fo = rg * 8;
    const size_t kbase = (size_t)b * Tq;

#pragma unroll
    for (int it = 0; it < 24; ++it) {
        const int idx = it * 256 + tid;
        const int n  = idx >> 5;
        const int c8 = (idx & 31) * 8;
        uint4 v = {0, 0, 0, 0};
        const int u = u0 + n;
        if (u >= 0) v = *(const uint4*)(kbf + (kbase + u) * (size_t)Hq + c8);
        *(uint4*)&Ks[((c8 >> 5) * KW + n) * 32 + (c8 & 31)] = v;
    }
    __syncthreads();

    f32x4 acc[12] = {};
    const bf16_t* qrow = qsbf + (kbase + t0 + 16 * w + fr) * (size_t)Hq;
#pragma unroll
    for (int ks = 0; ks < 8; ++ks) {
        const bf16x8 aq = *(const bf16x8*)(qrow + ks * 32 + fo);
#pragma unroll
        for (int jf = 0; jf < 12; ++jf) {
            const bf16x8 bk = *(const bf16x8*)&Ks[(ks * KW + jf * 16 + fr) * 32 + fo];
            acc[jf] = __builtin_amdgcn_mfma_f32_16x16x32_bf16(aq, bk, acc[jf], 0, 0, 0);
        }
    }

    const int jmin = (128 - t0) > 0 ? (128 - t0) : 0;
    float mx[4] = {-3e38f, -3e38f, -3e38f, -3e38f};
#pragma unroll
    for (int jf = 0; jf < 12; ++jf)
#pragma unroll
        for (int r = 0; r < 4; ++r) {
            const int i = 16 * w + rg * 4 + r;
            const int j = jf * 16 + fr;
            if (j >= i && j <= i + 128 && j >= jmin)
                mx[r] = fmaxf(mx[r], acc[jf][r]);
        }
#pragma unroll
    for (int d = 1; d < 16; d <<= 1)
#pragma unroll
        for (int r = 0; r < 4; ++r) mx[r] = fmaxf(mx[r], __shfl_xor(mx[r], d));

    float ex[12][4];
    float sm[4] = {0.0f, 0.0f, 0.0f, 0.0f};
#pragma unroll
    for (int jf = 0; jf < 12; ++jf)
#pragma unroll
        for (int r = 0; r < 4; ++r) {
            const int i = 16 * w + rg * 4 + r;
            const int j = jf * 16 + fr;
            const bool v = (j >= i && j <= i + 128 && j >= jmin);
            const float e = v ? __expf(acc[jf][r] - mx[r]) : 0.0f;
            ex[jf][r] = e;
            sm[r] += e;
        }
#pragma unroll
    for (int d = 1; d < 16; d <<= 1)
#pragma unroll
        for (int r = 0; r < 4; ++r) sm[r] += __shfl_xor(sm[r], d);
    float inv[4];
#pragma unroll
    for (int r = 0; r < 4; ++r) inv[r] = 1.0f / (sm[r] + 1e-10f);

#pragma unroll
    for (int jf = 0; jf < 12; ++jf)
#pragma unroll
        for (int r = 0; r < 4; ++r) {
            const int i = 16 * w + rg * 4 + r;
            const int j = jf * 16 + fr;
            const float wv = ex[jf][r] * inv[r];
            if (u0 + j >= 0)
                out1[(kbase + t0 + i) * (size_t)Tq + (u0 + j)] = wv;
            P[((j >> 5) * 64 + i) * PLD + (j & 31)] = (bf16_t)wv;
        }

    f32x4 cacc[16] = {};
    for (int jc = 0; jc < 6; ++jc) {
        __syncthreads();
#pragma unroll
        for (int it = 0; it < 4; ++it) {
            const int idx = it * 256 + tid;
            const int jl = idx >> 5;
            const int hc = (idx & 31) * 8;
            const bf16x8 kv = *(const bf16x8*)&Ks[((hc >> 5) * KW + jc * 32 + jl) * 32 + (hc & 31)];
#pragma unroll
            for (int e = 0; e < 8; ++e) KT[(hc + e) * KTLD + jl] = kv[e];
        }
        __syncthreads();
        const bf16x8 pa = *(const bf16x8*)&P[(jc * 64 + 16 * w + fr) * PLD + fo];
#pragma unroll
        for (int hf = 0; hf < 16; ++hf) {
            const bf16x8 bk = *(const bf16x8*)&KT[(hf * 16 + fr) * KTLD + fo];
            cacc[hf] = __builtin_amdgcn_mfma_f32_16x16x32_bf16(pa, bk, cacc[hf], 0, 0, 0);
        }
    }

#pragma unroll
    for (int hf = 0; hf < 16; ++hf)
#pragma unroll
        for (int r = 0; r < 4; ++r) {
            const int i = 16 * w + rg * 4 + r;
            c_att[(kbase + t0 + i) * (size_t)Hq + hf * 16 + fr] = (bf16_t)cacc[hf][r];
        }
}

// ---------------------------------------------------------------------------
extern "C" void kernel_launch(void* const* d_in, const int* in_sizes, int n_in,
                              void* d_out, int out_size, void* d_ws, size_t ws_size,
                              hipStream_t stream)
{
    (void)in_sizes; (void)n_in; (void)out_size; (void)ws_size;
    const float* x        = (const float*)d_in[0];
    const float* feat_w   = (const float*)d_in[1];
    const float* feat_b   = (const float*)d_in[2];
    const float* k_Wih    = (const float*)d_in[3];
    const float* k_Whh    = (const float*)d_in[4];
    const float* k_bih    = (const float*)d_in[5];
    const float* k_bhh    = (const float*)d_in[6];
    const float* q_Wih    = (const float*)d_in[7];
    const float* q_Whh    = (const float*)d_in[8];
    const float* q_bih    = (const float*)d_in[9];
    const float* q_bhh    = (const float*)d_in[10];
    const float* score_w  = (const float*)d_in[11];
    const float* enhance_w= (const float*)d_in[12];
    const float* enhance_b= (const float*)d_in[13];
    const float* mask_w   = (const float*)d_in[14];
    const float* mask_b   = (const float*)d_in[15];

    float* out0 = (float*)d_out;                         // (8,2048,257)
    float* out1 = out0 + (size_t)Bq * Tq * Fq;           // (8,2048,2048)

    // ---- workspace (no fills needed; every word written before read) ----
    float* cst      = (float*)d_ws;                      // 2*TH f32 (c states)
    float* bias_all = cst + (size_t)2 * TH;              // 2048 f32
    bf16_t* cvd = (bf16_t*)(bias_all + 2048);
    bf16_t* xbf     = cvd;                               // reused as qsbf later
    bf16_t* featw   = cvd + CV_O1;
    bf16_t* Wall    = cvd + CV_O2;                       // 2048 rows x 512 [k;q]
    bf16_t* scw     = cvd + CV_O4;
    bf16_t* enw     = cvd + CV_O5;
    bf16_t* mkw     = cvd + CV_O6;
    bf16_t* hfeatbf = cvd + CV_TOT;                      // Mq*256 (reused as out_h)
    bf16_t* hkbf    = hfeatbf + (size_t)Mq * Hq;         // 8*TH
    bf16_t* hqbf    = hkbf + (size_t)Bq * TH;            // 8*TH
    bf16_t* cattb   = hqbf + (size_t)Bq * TH;            // Mq*256

    // 0) conversions + bias fold (one dispatch)
    cvt_all<<<CVB + 1, 256, 0, stream>>>(
        x, feat_w, k_Wih, k_Whh, q_Wih, q_Whh, score_w, enhance_w, mask_w, cvd,
        k_bih, k_bhh, q_bih, q_bhh, bias_all);

    // 1) feat: hfeatbf = tanh(x @ feat_w^T + feat_b)   grid (2, 256)
    gemm_mfma<1, false, true, false><<<dim3(2, Mq / 64), 256, 0, stream>>>(
        xbf, 288, 288, nullptr, 0, 0, featw, feat_b, nullptr, 0,
        nullptr, hfeatbf, Hq, 1 << 30);

    // 2) LSTM k & q: 8 fused steps; step b also zero-fills out1 batch b
    lstm_step<true><<<dim3(8, Tq / 64, 2), 256, 0, stream>>>(
        hfeatbf, nullptr, nullptr, Wall, bias_all, cst, hkbf, hqbf, out1);
    for (int b = 1; b < Bq; ++b)
        lstm_step<false><<<dim3(8, Tq / 64, 2), 256, 0, stream>>>(
            hfeatbf + (size_t)b * TH,
            hkbf + (size_t)(b - 1) * TH, hqbf + (size_t)(b - 1) * TH,
            Wall, bias_all, cst,
            hkbf + (size_t)b * TH, hqbf + (size_t)b * TH,
            out1 + (size_t)b * Tq * Tq);

    // 3) score: qsbf = q @ score_w^T  (bf16, reuses xbf)  grid (2, 256)
    bf16_t* qsbf = xbf;
    gemm_mfma<0, false, true, false><<<dim3(2, Mq / 64), 256, 0, stream>>>(
        hqbf, Hq, Hq, nullptr, 0, 0, scw, nullptr, nullptr, 0,
        nullptr, qsbf, Hq, 1 << 30);

    // 4+5) fused banded softmax + PV; writes only the band windows
    band_fused<<<dim3(Tq / 64, Bq), 256, 0, stream>>>(qsbf, hkbf, out1, cattb);

    // 6) enhance: out_h = tanh([c, q] @ enhance_w^T + b)  grid (2, 256)
    bf16_t* outh = hfeatbf;
    gemm_mfma<1, false, true, false><<<dim3(2, Mq / 64), 256, 0, stream>>>(
        cattb, Hq, Hq, hqbf, Hq, Hq, enw, enhance_b, nullptr, 0,
        nullptr, outh, Hq, 1 << 30);

    // 7) mask + final: out0 = x * sigmoid(out_h @ mask_w^T + mask_b)  grid (3, 256)
    gemm_mfma<2, true, false, true><<<dim3(3, Mq / 64), 256, 0, stream>>>(
        outh, Hq, Hq, nullptr, 0, 0, mkw, mask_b, x, Fq,
        out0, nullptr, Fq, Fq);
}